// Round 2
// baseline (639.734 us; speedup 1.0000x reference)
//
#include <hip/hip_runtime.h>

// PointNetFP: three_nn_interpolate -> concat -> conv_bn_relu x2 (training-mode BN)
// Sizes fixed per setup_inputs(): B=8, N=8192, M=2048, C=256, C2=256, O1=O2=256.
//
// Pipeline:
//  1. k_transpose : w1[256][512] -> w1t[512][256]; w2 -> w2t (coalesced GEMM staging)
//  2. k_threenn   : per-point top-3 nearest centers (LDS-staged centers) -> idx, weights
//  3. k_interp    : gather+weight center features -> interp [B][256][N] (ws)
//  4. k_gemm1     : y1 = w1 @ concat(interp, pf) -> d_out (raw, pre-BN) + per-block (sum,sumsq)
//  5. k_params    : BN1 batch stats -> (scale, shift) per channel (conv bias cancels under BN)
//  6. k_gemm2     : x1 = relu(y1*sc+sh) applied in staging; y2 = w2 @ x1 -> d_out IN-PLACE
//                   (safe: each block reads exactly the columns it writes, reads precede writes)
//  7. k_params    : BN2 stats
//  8. k_final     : in-place relu(y2*sc2+sh2) on d_out
//  9. memcpyAsync : points_coords -> tail of d_out
//
// GEMM tile: 256 threads, block computes [O=256][n=128]. Thread micro-tile 8o x 16n:
// acc f4[2][4][4] (=128 VGPR), o = oj*128 + to*4 + i, n = jj*32 + tn*4 + r.
// ~0.75 B LDS-read per FMA -> FMA-pipe bound (no fp32 MFMA on CDNA4).

#define BB 8
#define NN 8192
#define MM 2048
#define CF 256
#define CP 256
#define O1 256
#define O2 256

typedef float f4 __attribute__((ext_vector_type(4)));

// ---- workspace layout (bytes), total ~69 MB ----
#define OFF_IDX    ((size_t)0)                                   // int [B*N][4]      1 MB
#define OFF_WGT    ((size_t)1 << 20)                             // float [B*N][4]    1 MB
#define OFF_INTERP ((size_t)2 << 20)                             // float [B][256][N] 64 MB
#define OFF_P1S    (OFF_INTERP + (size_t)BB*CF*NN*4)             // float [512][256]
#define OFF_P1Q    (OFF_P1S + (size_t)512*256*4)
#define OFF_P2S    (OFF_P1Q + (size_t)512*256*4)
#define OFF_P2Q    (OFF_P2S + (size_t)512*256*4)
#define OFF_PAR1   (OFF_P2Q + (size_t)512*256*4)                 // float2 [256]
#define OFF_PAR2   (OFF_PAR1 + (size_t)256*8)
#define OFF_W1T    (OFF_PAR2 + (size_t)256*8)                    // float [512][256]
#define OFF_W2T    (OFF_W1T + (size_t)512*256*4)                 // float [256][256]

__device__ __forceinline__ f4 relu4(f4 v) {
    v.x = fmaxf(v.x, 0.f); v.y = fmaxf(v.y, 0.f);
    v.z = fmaxf(v.z, 0.f); v.w = fmaxf(v.w, 0.f);
    return v;
}

// ---- 1. weight transposes ----
__global__ void k_transpose(const float* __restrict__ w1, const float* __restrict__ w2,
                            float* __restrict__ w1t, float* __restrict__ w2t) {
    int i = blockIdx.x * 256 + threadIdx.x;          // grid covers 512*256 + 256*256
    if (i < 512 * 256) {
        int c = i >> 8, o = i & 255;
        w1t[c * 256 + o] = w1[o * 512 + c];
    } else {
        int j = i - 512 * 256;
        int c = j >> 8, o = j & 255;
        w2t[c * 256 + o] = w2[o * 256 + c];
    }
}

// ---- 2. three-NN ----
__global__ __launch_bounds__(128) void k_threenn(const float* __restrict__ pc,
                                                 const float* __restrict__ cen,
                                                 int* __restrict__ idx,
                                                 float* __restrict__ wgt) {
    __shared__ f4 c4[MM];                            // (x,y,z,0) packed: 32 KB
    const int b  = blockIdx.x >> 6;
    const int n0 = (blockIdx.x & 63) << 7;           // 64 chunks of 128 points
    const float* cb = cen + b * 3 * MM;
    for (int m = threadIdx.x; m < MM; m += 128) {
        f4 v = {cb[m], cb[MM + m], cb[2 * MM + m], 0.f};
        c4[m] = v;
    }
    __syncthreads();
    const int n = n0 + threadIdx.x;
    const float* pb = pc + b * 3 * NN;
    const float px = pb[n], py = pb[NN + n], pz = pb[2 * NN + n];
    float d0 = 3e38f, d1 = 3e38f, d2 = 3e38f;
    int   i0 = 0,    i1 = 0,    i2 = 0;
    for (int m = 0; m < MM; ++m) {
        f4 cm = c4[m];
        float dx = px - cm.x, dy = py - cm.y, dz = pz - cm.z;
        float d = fmaf(dz, dz, fmaf(dy, dy, dx * dx));
        if (d < d2) {                                 // strict <: keeps lowest index on ties (matches top_k)
            if (d < d1) {
                d2 = d1; i2 = i1;
                if (d < d0) { d1 = d0; i1 = i0; d0 = d; i0 = m; }
                else        { d1 = d;  i1 = m; }
            } else { d2 = d; i2 = m; }
        }
    }
    float w0 = 1.f / (d0 + 1e-8f), w1 = 1.f / (d1 + 1e-8f), w2 = 1.f / (d2 + 1e-8f);
    float inv = 1.f / (w0 + w1 + w2);
    const int p = b * NN + n;
    *(int4*)(idx + p * 4) = make_int4(i0, i1, i2, 0);
    f4 wv = {w0 * inv, w1 * inv, w2 * inv, 0.f};
    *(f4*)(wgt + p * 4) = wv;
}

// ---- 3. gather-interpolate: interp[b][c][n] = sum_k w_k * cf[b][c][idx_k] ----
__global__ __launch_bounds__(256) void k_interp(const float* __restrict__ cf,
                                                const int* __restrict__ idx,
                                                const float* __restrict__ wgt,
                                                float* __restrict__ itp) {
    const int b  = blockIdx.x >> 7;                  // 128 chunks of 64 points per batch
    const int n0 = (blockIdx.x & 127) << 6;
    const int pp = threadIdx.x & 63;                 // point within chunk (wave = one c-slice)
    const int cq = threadIdx.x >> 6;                 // 4 channel quarters
    const int p = b * NN + n0 + pp;
    const int4 iv = *(const int4*)(idx + p * 4);
    const f4   wv = *(const f4*)(wgt + p * 4);
    const float* cb = cf + b * CF * MM;
    float* op = itp + b * CF * NN + n0 + pp;
    #pragma unroll 2
    for (int cc = 0; cc < 64; ++cc) {
        const int c = cq * 64 + cc;
        const float* row = cb + c * MM;
        op[c * NN] = row[iv.x] * wv.x + row[iv.y] * wv.y + row[iv.z] * wv.z;
    }
}

// ---- GEMM compute core (macro params deliberately avoid x/y/z/w tokens!) ----
// XS: [16][128] f32, WS: [16][256] f32
#define GEMM_COMPUTE(ACC, XS, WS, TO, TN)                                      \
    _Pragma("unroll")                                                          \
    for (int cc = 0; cc < 16; ++cc) {                                          \
        f4 wv0 = *(const f4*)&WS[cc * 256 + (TO << 2)];                        \
        f4 wv1 = *(const f4*)&WS[cc * 256 + 128 + (TO << 2)];                  \
        f4 xv[4];                                                              \
        _Pragma("unroll")                                                      \
        for (int jj = 0; jj < 4; ++jj)                                         \
            xv[jj] = *(const f4*)&XS[cc * 128 + jj * 32 + (TN << 2)];          \
        _Pragma("unroll")                                                      \
        for (int i = 0; i < 4; ++i) {                                          \
            float wa = wv0[i], wb = wv1[i];                                    \
            _Pragma("unroll")                                                  \
            for (int jj = 0; jj < 4; ++jj) {                                   \
                ACC[0][i][jj] += xv[jj] * wa;                                  \
                ACC[1][i][jj] += xv[jj] * wb;                                  \
            }                                                                  \
        }                                                                      \
    }

// epilogue: per-block channel partials (sum, sumsq) + raw y store
#define GEMM_EPILOGUE(ACC, YP, PS, PQ, BQ, N0, TO, TN, OCH)                    \
    {                                                                          \
        float rs_[2][4], rq_[2][4];                                            \
        _Pragma("unroll")                                                      \
        for (int oj = 0; oj < 2; ++oj)                                         \
            _Pragma("unroll")                                                  \
            for (int i = 0; i < 4; ++i) {                                      \
                float ss = 0.f, qq = 0.f;                                      \
                _Pragma("unroll")                                              \
                for (int jj = 0; jj < 4; ++jj) {                               \
                    f4 a = ACC[oj][i][jj];                                     \
                    ss += a[0] + a[1] + a[2] + a[3];                           \
                    qq += a[0]*a[0] + a[1]*a[1] + a[2]*a[2] + a[3]*a[3];       \
                }                                                              \
                rs_[oj][i] = ss; rq_[oj][i] = qq;                              \
            }                                                                  \
        _Pragma("unroll")                                                      \
        for (int m = 1; m < 8; m <<= 1) {                                      \
            _Pragma("unroll")                                                  \
            for (int oj = 0; oj < 2; ++oj)                                     \
                _Pragma("unroll")                                              \
                for (int i = 0; i < 4; ++i) {                                  \
                    rs_[oj][i] += __shfl_xor(rs_[oj][i], m, 64);               \
                    rq_[oj][i] += __shfl_xor(rq_[oj][i], m, 64);               \
                }                                                              \
        }                                                                      \
        if (TN == 0) {                                                         \
            _Pragma("unroll")                                                  \
            for (int oj = 0; oj < 2; ++oj) {                                   \
                f4 vs = {rs_[oj][0], rs_[oj][1], rs_[oj][2], rs_[oj][3]};      \
                f4 vq = {rq_[oj][0], rq_[oj][1], rq_[oj][2], rq_[oj][3]};      \
                int o0 = oj * 128 + (TO << 2);                                 \
                *(f4*)(PS + blockIdx.x * 256 + o0) = vs;                       \
                *(f4*)(PQ + blockIdx.x * 256 + o0) = vq;                       \
            }                                                                  \
        }                                                                      \
        float* yb_ = YP + ((size_t)BQ * OCH * NN) + N0;                        \
        _Pragma("unroll")                                                      \
        for (int oj = 0; oj < 2; ++oj)                                         \
            _Pragma("unroll")                                                  \
            for (int i = 0; i < 4; ++i) {                                      \
                float* row_ = yb_ + (oj * 128 + (TO << 2) + i) * NN;           \
                _Pragma("unroll")                                              \
                for (int jj = 0; jj < 4; ++jj)                                 \
                    *(f4*)(row_ + jj * 32 + (TN << 2)) = ACC[oj][i][jj];       \
            }                                                                  \
    }

// ---- 4. GEMM1: y1 = w1 @ [interp ; pf], raw (bias dropped: cancels under BN) ----
__global__ __launch_bounds__(256, 2) void k_gemm1(const float* __restrict__ xa,
                                                  const float* __restrict__ xb,
                                                  const float* __restrict__ wt,
                                                  float* __restrict__ yo,
                                                  float* __restrict__ ps,
                                                  float* __restrict__ pq) {
    __shared__ __align__(16) float xs[16 * 128];
    __shared__ __align__(16) float wsm[16 * 256];
    const int tid = threadIdx.x;
    const int b  = blockIdx.x >> 6;
    const int n0 = (blockIdx.x & 63) << 7;
    const int tn = tid & 7, to = tid >> 3;
    f4 acc[2][4][4];
    f4 zero = {0.f, 0.f, 0.f, 0.f};
    #pragma unroll
    for (int oj = 0; oj < 2; ++oj)
        #pragma unroll
        for (int i = 0; i < 4; ++i)
            #pragma unroll
            for (int jj = 0; jj < 4; ++jj) acc[oj][i][jj] = zero;

    for (int ct = 0; ct < 32; ++ct) {
        const float* xsrc = (ct < 16) ? (xa + (b * CF + ct * 16) * NN + n0)
                                      : (xb + (b * CP + (ct - 16) * 16) * NN + n0);
        if (ct) __syncthreads();
        #pragma unroll
        for (int k = 0; k < 2; ++k) {                 // x tile: 16 rows x 128
            int e4 = k * 256 + tid;
            int cc = e4 >> 5, nn4 = (e4 & 31) << 2;
            *(f4*)&xs[cc * 128 + nn4] = *(const f4*)(xsrc + cc * NN + nn4);
        }
        const float* wsrc = wt + ct * 16 * 256;       // w tile: contiguous 4096 floats
        #pragma unroll
        for (int k = 0; k < 4; ++k) {
            int e4 = k * 256 + tid;
            *(f4*)&wsm[e4 << 2] = *(const f4*)(wsrc + (e4 << 2));
        }
        __syncthreads();
        GEMM_COMPUTE(acc, xs, wsm, to, tn)
    }
    GEMM_EPILOGUE(acc, yo, ps, pq, b, n0, to, tn, O1)
}

// ---- 6. GEMM2: x1 = relu(BN(y1)) applied in staging; IN-PLACE on y (d_out) ----
__global__ __launch_bounds__(256, 2) void k_gemm2(float* yio,   // no restrict: in-place
                                                  const float* __restrict__ wt,
                                                  const float2* __restrict__ par1,
                                                  float* __restrict__ ps,
                                                  float* __restrict__ pq) {
    __shared__ __align__(16) float xs[16 * 128];
    __shared__ __align__(16) float wsm[16 * 256];
    const int tid = threadIdx.x;
    const int b  = blockIdx.x >> 6;
    const int n0 = (blockIdx.x & 63) << 7;
    const int tn = tid & 7, to = tid >> 3;
    f4 acc[2][4][4];
    f4 zero = {0.f, 0.f, 0.f, 0.f};
    #pragma unroll
    for (int oj = 0; oj < 2; ++oj)
        #pragma unroll
        for (int i = 0; i < 4; ++i)
            #pragma unroll
            for (int jj = 0; jj < 4; ++jj) acc[oj][i][jj] = zero;

    for (int ct = 0; ct < 16; ++ct) {
        if (ct) __syncthreads();
        #pragma unroll
        for (int k = 0; k < 2; ++k) {
            int e4 = k * 256 + tid;
            int cc = e4 >> 5, nn4 = (e4 & 31) << 2;
            int c = ct * 16 + cc;
            f4 v = *(const f4*)(yio + ((size_t)b * O1 + c) * NN + n0 + nn4);
            float2 pr = par1[c];
            v = relu4(v * pr.x + pr.y);
            *(f4*)&xs[cc * 128 + nn4] = v;
        }
        const float* wsrc = wt + ct * 16 * 256;
        #pragma unroll
        for (int k = 0; k < 4; ++k) {
            int e4 = k * 256 + tid;
            *(f4*)&wsm[e4 << 2] = *(const f4*)(wsrc + (e4 << 2));
        }
        __syncthreads();
        GEMM_COMPUTE(acc, xs, wsm, to, tn)
    }
    GEMM_EPILOGUE(acc, yio, ps, pq, b, n0, to, tn, O2)
}

// ---- 5/7. BN stats -> per-channel (scale, shift) ----
__global__ void k_params(const float* __restrict__ ps, const float* __restrict__ pq,
                         const float* __restrict__ gamma, const float* __restrict__ beta,
                         float2* __restrict__ out) {
    __shared__ float rs[256], rq[256];
    const int oo = threadIdx.x & 15, seg = threadIdx.x >> 4;
    const int o = blockIdx.x * 16 + oo;
    float s = 0.f, q = 0.f;
    for (int blk = seg; blk < 512; blk += 16) {
        s += ps[blk * 256 + o];
        q += pq[blk * 256 + o];
    }
    rs[threadIdx.x] = s; rq[threadIdx.x] = q;
    __syncthreads();
    if (seg == 0) {
        float S = 0.f, Q = 0.f;
        #pragma unroll
        for (int g = 0; g < 16; ++g) { S += rs[g * 16 + oo]; Q += rq[g * 16 + oo]; }
        float mean = S * (1.f / 65536.f);
        float var  = Q * (1.f / 65536.f) - mean * mean;
        float rstd = rsqrtf(var + 1e-5f);
        float sc = gamma[o] * rstd;
        out[o] = make_float2(sc, beta[o] - mean * sc);
    }
}

// ---- 8. final in-place BN+relu on d_out ----
__global__ __launch_bounds__(256) void k_final(float* __restrict__ yy,
                                               const float2* __restrict__ par) {
    int i = blockIdx.x * 256 + threadIdx.x;
    #pragma unroll 4
    for (int t = i; t < 4194304; t += 524288) {      // 16.7M floats as float4
        f4 v = ((f4*)yy)[t];
        float2 pr = par[(t >> 11) & 255];
        v = relu4(v * pr.x + pr.y);
        ((f4*)yy)[t] = v;
    }
}

extern "C" void kernel_launch(void* const* d_in, const int* in_sizes, int n_in,
                              void* d_out, int out_size, void* d_ws, size_t ws_size,
                              hipStream_t stream) {
    const float* pc  = (const float*)d_in[0];
    const float* cen = (const float*)d_in[1];
    const float* cf  = (const float*)d_in[2];
    const float* pf  = (const float*)d_in[3];
    const float* w1  = (const float*)d_in[4];
    const float* g1  = (const float*)d_in[6];
    const float* be1 = (const float*)d_in[7];
    const float* w2  = (const float*)d_in[8];
    const float* g2  = (const float*)d_in[10];
    const float* be2 = (const float*)d_in[11];

    char* ws = (char*)d_ws;
    int*    idx  = (int*)  (ws + OFF_IDX);
    float*  wgt  = (float*)(ws + OFF_WGT);
    float*  itp  = (float*)(ws + OFF_INTERP);
    float*  p1s  = (float*)(ws + OFF_P1S);
    float*  p1q  = (float*)(ws + OFF_P1Q);
    float*  p2s  = (float*)(ws + OFF_P2S);
    float*  p2q  = (float*)(ws + OFF_P2Q);
    float2* par1 = (float2*)(ws + OFF_PAR1);
    float2* par2 = (float2*)(ws + OFF_PAR2);
    float*  w1t  = (float*)(ws + OFF_W1T);
    float*  w2t  = (float*)(ws + OFF_W2T);
    float*  out  = (float*)d_out;

    k_transpose<<<768, 256, 0, stream>>>(w1, w2, w1t, w2t);
    k_threenn<<<512, 128, 0, stream>>>(pc, cen, idx, wgt);
    k_interp<<<1024, 256, 0, stream>>>(cf, idx, wgt, itp);
    k_gemm1<<<512, 256, 0, stream>>>(itp, pf, w1t, out, p1s, p1q);
    k_params<<<16, 256, 0, stream>>>(p1s, p1q, g1, be1, par1);
    k_gemm2<<<512, 256, 0, stream>>>(out, w2t, par1, p2s, p2q);
    k_params<<<16, 256, 0, stream>>>(p2s, p2q, g2, be2, par2);
    k_final<<<2048, 256, 0, stream>>>(out, par2);
    (void)hipMemcpyAsync(out + 16777216, pc, (size_t)BB * 3 * NN * 4,
                         hipMemcpyDeviceToDevice, stream);
}

// Round 3
// 491.342 us; speedup vs baseline: 1.3020x; 1.3020x over previous
//
#include <hip/hip_runtime.h>

// PointNetFP: three_nn_interpolate -> concat -> conv_bn_relu x2 (training-mode BN)
// Sizes fixed per setup_inputs(): B=8, N=8192, M=2048, C=256, C2=256, O1=O2=256.
//
// Pipeline:
//  1. k_transpose : w1[256][512] -> w1t[512][256]; w2 -> w2t (coalesced GEMM staging)
//  2. k_threenn   : per-point top-3 nearest centers -> idx, weights
//                   4 threads/point over 512-center subsets + shfl butterfly merge
//  3. k_interp    : gather+weight center features -> interp [B][256][N] (ws)
//  4. k_gemm1     : y1 = w1 @ concat(interp, pf) -> d_out (raw, pre-BN) + per-block (sum,sumsq)
//  5. k_params    : BN1 batch stats -> (scale, shift) per channel (conv bias cancels under BN)
//  6. k_gemm2     : x1 = relu(y1*sc+sh) applied in staging; y2 = w2 @ x1 -> d_out IN-PLACE
//  7. k_params    : BN2 stats
//  8. k_final     : in-place relu(y2*sc2+sh2) on d_out
//  9. memcpyAsync : points_coords -> tail of d_out

#define BB 8
#define NN 8192
#define MM 2048
#define CF 256
#define CP 256
#define O1 256
#define O2 256

typedef float f4 __attribute__((ext_vector_type(4)));

// ---- workspace layout (bytes), total ~69 MB ----
#define OFF_IDX    ((size_t)0)                                   // int [B*N][4]      1 MB
#define OFF_WGT    ((size_t)1 << 20)                             // float [B*N][4]    1 MB
#define OFF_INTERP ((size_t)2 << 20)                             // float [B][256][N] 64 MB
#define OFF_P1S    (OFF_INTERP + (size_t)BB*CF*NN*4)             // float [512][256]
#define OFF_P1Q    (OFF_P1S + (size_t)512*256*4)
#define OFF_P2S    (OFF_P1Q + (size_t)512*256*4)
#define OFF_P2Q    (OFF_P2S + (size_t)512*256*4)
#define OFF_PAR1   (OFF_P2Q + (size_t)512*256*4)                 // float2 [256]
#define OFF_PAR2   (OFF_PAR1 + (size_t)256*8)
#define OFF_W1T    (OFF_PAR2 + (size_t)256*8)                    // float [512][256]
#define OFF_W2T    (OFF_W1T + (size_t)512*256*4)                 // float [256][256]

__device__ __forceinline__ f4 relu4(f4 v) {
    v.x = fmaxf(v.x, 0.f); v.y = fmaxf(v.y, 0.f);
    v.z = fmaxf(v.z, 0.f); v.w = fmaxf(v.w, 0.f);
    return v;
}

// ---- 1. weight transposes ----
__global__ void k_transpose(const float* __restrict__ w1, const float* __restrict__ w2,
                            float* __restrict__ w1t, float* __restrict__ w2t) {
    int i = blockIdx.x * 256 + threadIdx.x;          // grid covers 512*256 + 256*256
    if (i < 512 * 256) {
        int c = i >> 8, o = i & 255;
        w1t[c * 256 + o] = w1[o * 512 + c];
    } else {
        int j = i - 512 * 256;
        int c = j >> 8, o = j & 255;
        w2t[c * 256 + o] = w2[o * 256 + c];
    }
}

// ---- 2. three-NN: 4 threads per point, branchless insert, shfl merge ----
// Strict-< insertion in ascending-m order == reference top_k tie behavior.
__device__ __forceinline__ void ins3(float d, int i,
                                     float& d0, int& i0, float& d1, int& i1,
                                     float& d2, int& i2) {
    bool c2 = d < d2, c1 = d < d1, c0 = d < d0;
    d2 = c1 ? d1 : (c2 ? d : d2);  i2 = c1 ? i1 : (c2 ? i : i2);
    d1 = c0 ? d0 : (c1 ? d : d1);  i1 = c0 ? i0 : (c1 ? i : i1);
    d0 = c0 ? d  : d0;             i0 = c0 ? i  : i0;
}

__global__ __launch_bounds__(256) void k_threenn(const float* __restrict__ pc,
                                                 const float* __restrict__ cen,
                                                 int* __restrict__ idx,
                                                 float* __restrict__ wgt) {
    __shared__ f4 c4[MM + 4];                        // +1 f4 pad per 512: subset bases 4 banks apart
    const int b  = blockIdx.x >> 7;                  // 128 blocks of 64 points per batch
    const int n0 = (blockIdx.x & 127) << 6;
    const float* cb = cen + b * 3 * MM;
    for (int m = threadIdx.x; m < MM; m += 256) {
        f4 v = {cb[m], cb[MM + m], cb[2 * MM + m], 0.f};
        c4[m + (m >> 9)] = v;
    }
    __syncthreads();
    const int pt  = threadIdx.x >> 2;                // point within chunk
    const int sub = threadIdx.x & 3;                 // center subset (same wave as partners)
    const int n = n0 + pt;
    const float* pb = pc + b * 3 * NN;
    const float px = pb[n], py = pb[NN + n], pz = pb[2 * NN + n];

    float d0 = 3e38f, d1 = 3e38f, d2 = 3e38f;
    int   i0 = 0,    i1 = 0,    i2 = 0;
    const f4* cbase = c4 + sub * 513;                // swizzled base, linear within subset
    const int m0 = sub * 512;
    for (int mm = 0; mm < 512; mm += 4) {
        f4 va = cbase[mm], vb = cbase[mm + 1], vc = cbase[mm + 2], vd = cbase[mm + 3];
        float xa = px - va.x, ya = py - va.y, za = pz - va.z;
        float xb2 = px - vb.x, yb2 = py - vb.y, zb2 = pz - vb.z;
        float xc = px - vc.x, yc = py - vc.y, zc = pz - vc.z;
        float xd = px - vd.x, yd = py - vd.y, zd = pz - vd.z;
        float da = fmaf(za, za, fmaf(ya, ya, xa * xa));
        float db = fmaf(zb2, zb2, fmaf(yb2, yb2, xb2 * xb2));
        float dc = fmaf(zc, zc, fmaf(yc, yc, xc * xc));
        float dd = fmaf(zd, zd, fmaf(yd, yd, xd * xd));
        float mn = fminf(fminf(da, db), fminf(dc, dd));
        if (mn < d2) {                               // rare after warm-up; amortized over 4
            const int mg = m0 + mm;
            ins3(da, mg,     d0, i0, d1, i1, d2, i2);
            ins3(db, mg + 1, d0, i0, d1, i1, d2, i2);
            ins3(dc, mg + 2, d0, i0, d1, i1, d2, i2);
            ins3(dd, mg + 3, d0, i0, d1, i1, d2, i2);
        }
    }
    // butterfly merge across the 4 subset-threads (lanes 4k..4k+3, same wave).
    // Partner triples are sorted ascending; inserting e0<=e1<=e2 sequentially is exact.
    #pragma unroll
    for (int m = 1; m <= 2; m <<= 1) {
        float e0 = __shfl_xor(d0, m), e1 = __shfl_xor(d1, m), e2 = __shfl_xor(d2, m);
        int   j0 = __shfl_xor(i0, m), j1 = __shfl_xor(i1, m), j2 = __shfl_xor(i2, m);
        ins3(e0, j0, d0, i0, d1, i1, d2, i2);
        ins3(e1, j1, d0, i0, d1, i1, d2, i2);
        ins3(e2, j2, d0, i0, d1, i1, d2, i2);
    }
    if (sub == 0) {
        float w0 = 1.f / (d0 + 1e-8f), w1 = 1.f / (d1 + 1e-8f), w2 = 1.f / (d2 + 1e-8f);
        float inv = 1.f / (w0 + w1 + w2);
        const int p = b * NN + n;
        *(int4*)(idx + p * 4) = make_int4(i0, i1, i2, 0);
        f4 wv = {w0 * inv, w1 * inv, w2 * inv, 0.f};
        *(f4*)(wgt + p * 4) = wv;
    }
}

// ---- 3. gather-interpolate: interp[b][c][n] = sum_k w_k * cf[b][c][idx_k] ----
__global__ __launch_bounds__(256) void k_interp(const float* __restrict__ cf,
                                                const int* __restrict__ idx,
                                                const float* __restrict__ wgt,
                                                float* __restrict__ itp) {
    const int b  = blockIdx.x >> 7;                  // 128 chunks of 64 points per batch
    const int n0 = (blockIdx.x & 127) << 6;
    const int pp = threadIdx.x & 63;                 // point within chunk (wave = one c-slice)
    const int cq = threadIdx.x >> 6;                 // 4 channel quarters
    const int p = b * NN + n0 + pp;
    const int4 iv = *(const int4*)(idx + p * 4);
    const f4   wv = *(const f4*)(wgt + p * 4);
    const float* cb = cf + b * CF * MM;
    float* op = itp + b * CF * NN + n0 + pp;
    #pragma unroll 2
    for (int cc = 0; cc < 64; ++cc) {
        const int c = cq * 64 + cc;
        const float* row = cb + c * MM;
        op[c * NN] = row[iv.x] * wv.x + row[iv.y] * wv.y + row[iv.z] * wv.z;
    }
}

// ---- GEMM compute core (macro params deliberately avoid x/y/z/w tokens!) ----
// XS: [16][128] f32, WS: [16][256] f32
#define GEMM_COMPUTE(ACC, XS, WS, TO, TN)                                      \
    _Pragma("unroll")                                                          \
    for (int cc = 0; cc < 16; ++cc) {                                          \
        f4 wv0 = *(const f4*)&WS[cc * 256 + (TO << 2)];                        \
        f4 wv1 = *(const f4*)&WS[cc * 256 + 128 + (TO << 2)];                  \
        f4 xv[4];                                                              \
        _Pragma("unroll")                                                      \
        for (int jj = 0; jj < 4; ++jj)                                         \
            xv[jj] = *(const f4*)&XS[cc * 128 + jj * 32 + (TN << 2)];          \
        _Pragma("unroll")                                                      \
        for (int i = 0; i < 4; ++i) {                                          \
            float wa = wv0[i], wb = wv1[i];                                    \
            _Pragma("unroll")                                                  \
            for (int jj = 0; jj < 4; ++jj) {                                   \
                ACC[0][i][jj] += xv[jj] * wa;                                  \
                ACC[1][i][jj] += xv[jj] * wb;                                  \
            }                                                                  \
        }                                                                      \
    }

// epilogue: per-block channel partials (sum, sumsq) + raw y store
#define GEMM_EPILOGUE(ACC, YP, PS, PQ, BQ, N0, TO, TN, OCH)                    \
    {                                                                          \
        float rs_[2][4], rq_[2][4];                                            \
        _Pragma("unroll")                                                      \
        for (int oj = 0; oj < 2; ++oj)                                         \
            _Pragma("unroll")                                                  \
            for (int i = 0; i < 4; ++i) {                                      \
                float ss = 0.f, qq = 0.f;                                      \
                _Pragma("unroll")                                              \
                for (int jj = 0; jj < 4; ++jj) {                               \
                    f4 a = ACC[oj][i][jj];                                     \
                    ss += a[0] + a[1] + a[2] + a[3];                           \
                    qq += a[0]*a[0] + a[1]*a[1] + a[2]*a[2] + a[3]*a[3];       \
                }                                                              \
                rs_[oj][i] = ss; rq_[oj][i] = qq;                              \
            }                                                                  \
        _Pragma("unroll")                                                      \
        for (int m = 1; m < 8; m <<= 1) {                                      \
            _Pragma("unroll")                                                  \
            for (int oj = 0; oj < 2; ++oj)                                     \
                _Pragma("unroll")                                              \
                for (int i = 0; i < 4; ++i) {                                  \
                    rs_[oj][i] += __shfl_xor(rs_[oj][i], m, 64);               \
                    rq_[oj][i] += __shfl_xor(rq_[oj][i], m, 64);               \
                }                                                              \
        }                                                                      \
        if (TN == 0) {                                                         \
            _Pragma("unroll")                                                  \
            for (int oj = 0; oj < 2; ++oj) {                                   \
                f4 vs = {rs_[oj][0], rs_[oj][1], rs_[oj][2], rs_[oj][3]};      \
                f4 vq = {rq_[oj][0], rq_[oj][1], rq_[oj][2], rq_[oj][3]};      \
                int o0 = oj * 128 + (TO << 2);                                 \
                *(f4*)(PS + blockIdx.x * 256 + o0) = vs;                       \
                *(f4*)(PQ + blockIdx.x * 256 + o0) = vq;                       \
            }                                                                  \
        }                                                                      \
        float* yb_ = YP + ((size_t)BQ * OCH * NN) + N0;                        \
        _Pragma("unroll")                                                      \
        for (int oj = 0; oj < 2; ++oj)                                         \
            _Pragma("unroll")                                                  \
            for (int i = 0; i < 4; ++i) {                                      \
                float* row_ = yb_ + (oj * 128 + (TO << 2) + i) * NN;           \
                _Pragma("unroll")                                              \
                for (int jj = 0; jj < 4; ++jj)                                 \
                    *(f4*)(row_ + jj * 32 + (TN << 2)) = ACC[oj][i][jj];       \
            }                                                                  \
    }

// ---- 4. GEMM1: y1 = w1 @ [interp ; pf], raw (bias dropped: cancels under BN) ----
__global__ __launch_bounds__(256, 2) void k_gemm1(const float* __restrict__ xa,
                                                  const float* __restrict__ xb,
                                                  const float* __restrict__ wt,
                                                  float* __restrict__ yo,
                                                  float* __restrict__ ps,
                                                  float* __restrict__ pq) {
    __shared__ __align__(16) float xs[16 * 128];
    __shared__ __align__(16) float wsm[16 * 256];
    const int tid = threadIdx.x;
    const int b  = blockIdx.x >> 6;
    const int n0 = (blockIdx.x & 63) << 7;
    const int tn = tid & 7, to = tid >> 3;
    f4 acc[2][4][4];
    f4 zero = {0.f, 0.f, 0.f, 0.f};
    #pragma unroll
    for (int oj = 0; oj < 2; ++oj)
        #pragma unroll
        for (int i = 0; i < 4; ++i)
            #pragma unroll
            for (int jj = 0; jj < 4; ++jj) acc[oj][i][jj] = zero;

    for (int ct = 0; ct < 32; ++ct) {
        const float* xsrc = (ct < 16) ? (xa + (b * CF + ct * 16) * NN + n0)
                                      : (xb + (b * CP + (ct - 16) * 16) * NN + n0);
        if (ct) __syncthreads();
        #pragma unroll
        for (int k = 0; k < 2; ++k) {                 // x tile: 16 rows x 128
            int e4 = k * 256 + tid;
            int cc = e4 >> 5, nn4 = (e4 & 31) << 2;
            *(f4*)&xs[cc * 128 + nn4] = *(const f4*)(xsrc + cc * NN + nn4);
        }
        const float* wsrc = wt + ct * 16 * 256;       // w tile: contiguous 4096 floats
        #pragma unroll
        for (int k = 0; k < 4; ++k) {
            int e4 = k * 256 + tid;
            *(f4*)&wsm[e4 << 2] = *(const f4*)(wsrc + (e4 << 2));
        }
        __syncthreads();
        GEMM_COMPUTE(acc, xs, wsm, to, tn)
    }
    GEMM_EPILOGUE(acc, yo, ps, pq, b, n0, to, tn, O1)
}

// ---- 6. GEMM2: x1 = relu(BN(y1)) applied in staging; IN-PLACE on y (d_out) ----
__global__ __launch_bounds__(256, 2) void k_gemm2(float* yio,   // no restrict: in-place
                                                  const float* __restrict__ wt,
                                                  const float2* __restrict__ par1,
                                                  float* __restrict__ ps,
                                                  float* __restrict__ pq) {
    __shared__ __align__(16) float xs[16 * 128];
    __shared__ __align__(16) float wsm[16 * 256];
    const int tid = threadIdx.x;
    const int b  = blockIdx.x >> 6;
    const int n0 = (blockIdx.x & 63) << 7;
    const int tn = tid & 7, to = tid >> 3;
    f4 acc[2][4][4];
    f4 zero = {0.f, 0.f, 0.f, 0.f};
    #pragma unroll
    for (int oj = 0; oj < 2; ++oj)
        #pragma unroll
        for (int i = 0; i < 4; ++i)
            #pragma unroll
            for (int jj = 0; jj < 4; ++jj) acc[oj][i][jj] = zero;

    for (int ct = 0; ct < 16; ++ct) {
        if (ct) __syncthreads();
        #pragma unroll
        for (int k = 0; k < 2; ++k) {
            int e4 = k * 256 + tid;
            int cc = e4 >> 5, nn4 = (e4 & 31) << 2;
            int c = ct * 16 + cc;
            f4 v = *(const f4*)(yio + ((size_t)b * O1 + c) * NN + n0 + nn4);
            float2 pr = par1[c];
            v = relu4(v * pr.x + pr.y);
            *(f4*)&xs[cc * 128 + nn4] = v;
        }
        const float* wsrc = wt + ct * 16 * 256;
        #pragma unroll
        for (int k = 0; k < 4; ++k) {
            int e4 = k * 256 + tid;
            *(f4*)&wsm[e4 << 2] = *(const f4*)(wsrc + (e4 << 2));
        }
        __syncthreads();
        GEMM_COMPUTE(acc, xs, wsm, to, tn)
    }
    GEMM_EPILOGUE(acc, yio, ps, pq, b, n0, to, tn, O2)
}

// ---- 5/7. BN stats -> per-channel (scale, shift) ----
__global__ void k_params(const float* __restrict__ ps, const float* __restrict__ pq,
                         const float* __restrict__ gamma, const float* __restrict__ beta,
                         float2* __restrict__ out) {
    __shared__ float rs[256], rq[256];
    const int oo = threadIdx.x & 15, seg = threadIdx.x >> 4;
    const int o = blockIdx.x * 16 + oo;
    float s = 0.f, q = 0.f;
    for (int blk = seg; blk < 512; blk += 16) {
        s += ps[blk * 256 + o];
        q += pq[blk * 256 + o];
    }
    rs[threadIdx.x] = s; rq[threadIdx.x] = q;
    __syncthreads();
    if (seg == 0) {
        float S = 0.f, Q = 0.f;
        #pragma unroll
        for (int g = 0; g < 16; ++g) { S += rs[g * 16 + oo]; Q += rq[g * 16 + oo]; }
        float mean = S * (1.f / 65536.f);
        float var  = Q * (1.f / 65536.f) - mean * mean;
        float rstd = rsqrtf(var + 1e-5f);
        float sc = gamma[o] * rstd;
        out[o] = make_float2(sc, beta[o] - mean * sc);
    }
}

// ---- 8. final in-place BN+relu on d_out ----
__global__ __launch_bounds__(256) void k_final(float* __restrict__ yy,
                                               const float2* __restrict__ par) {
    int i = blockIdx.x * 256 + threadIdx.x;
    #pragma unroll 4
    for (int t = i; t < 4194304; t += 524288) {      // 16.7M floats as float4
        f4 v = ((f4*)yy)[t];
        float2 pr = par[(t >> 11) & 255];
        v = relu4(v * pr.x + pr.y);
        ((f4*)yy)[t] = v;
    }
}

extern "C" void kernel_launch(void* const* d_in, const int* in_sizes, int n_in,
                              void* d_out, int out_size, void* d_ws, size_t ws_size,
                              hipStream_t stream) {
    const float* pc  = (const float*)d_in[0];
    const float* cen = (const float*)d_in[1];
    const float* cf  = (const float*)d_in[2];
    const float* pf  = (const float*)d_in[3];
    const float* w1  = (const float*)d_in[4];
    const float* g1  = (const float*)d_in[6];
    const float* be1 = (const float*)d_in[7];
    const float* w2  = (const float*)d_in[8];
    const float* g2  = (const float*)d_in[10];
    const float* be2 = (const float*)d_in[11];

    char* ws = (char*)d_ws;
    int*    idx  = (int*)  (ws + OFF_IDX);
    float*  wgt  = (float*)(ws + OFF_WGT);
    float*  itp  = (float*)(ws + OFF_INTERP);
    float*  p1s  = (float*)(ws + OFF_P1S);
    float*  p1q  = (float*)(ws + OFF_P1Q);
    float*  p2s  = (float*)(ws + OFF_P2S);
    float*  p2q  = (float*)(ws + OFF_P2Q);
    float2* par1 = (float2*)(ws + OFF_PAR1);
    float2* par2 = (float2*)(ws + OFF_PAR2);
    float*  w1t  = (float*)(ws + OFF_W1T);
    float*  w2t  = (float*)(ws + OFF_W2T);
    float*  out  = (float*)d_out;

    k_transpose<<<768, 256, 0, stream>>>(w1, w2, w1t, w2t);
    k_threenn<<<1024, 256, 0, stream>>>(pc, cen, idx, wgt);
    k_interp<<<1024, 256, 0, stream>>>(cf, idx, wgt, itp);
    k_gemm1<<<512, 256, 0, stream>>>(itp, pf, w1t, out, p1s, p1q);
    k_params<<<16, 256, 0, stream>>>(p1s, p1q, g1, be1, par1);
    k_gemm2<<<512, 256, 0, stream>>>(out, w2t, par1, p2s, p2q);
    k_params<<<16, 256, 0, stream>>>(p2s, p2q, g2, be2, par2);
    k_final<<<2048, 256, 0, stream>>>(out, par2);
    (void)hipMemcpyAsync(out + 16777216, pc, (size_t)BB * 3 * NN * 4,
                         hipMemcpyDeviceToDevice, stream);
}

// Round 4
// 288.882 us; speedup vs baseline: 2.2145x; 1.7008x over previous
//
#include <hip/hip_runtime.h>

// PointNetFP: three_nn_interpolate -> concat -> conv_bn_relu x2 (training-mode BN)
// B=8, N=8192, M=2048, C=256, C2=256, O1=O2=256.
//
// Pipeline:
//  1. k_wsplit  : split w1/w2 into bf16 hi/lo, pre-swizzled per-32k-step LDS image
//  2. k_threenn : per-point top-3 nearest centers (4 thr/point + shfl merge)
//  3. k_interp  : gather+weight center features -> interp [B][256][N] f32 (ws)
//  4. k_gemm<512,false>: y1 = w1 @ [interp;pf] via split-bf16 MFMA (3 products)
//                        -> d_out raw + per-block BN partials
//  5. k_params  : BN1 stats -> (scale, shift)   (conv bias cancels under BN)
//  6. k_gemm<256,true> : x1 = relu(BN(y1)) in staging; y2 = w2 @ x1 IN-PLACE on d_out
//  7. k_params  : BN2 stats
//  8. k_final   : in-place relu(y2*sc+sh)
//  9. memcpyAsync: points_coords -> tail of d_out
//
// GEMM geometry: block [O=256][n=128], wave [64 o][128 n] = 4x8 16x16x32 frags,
// acc 128 VGPR. Split MFMA: acc += Ah*Bh + Al*Bh + Ah*Bl (lo*lo ~2^-18 dropped).
// LDS image rows = 128B = 8 slots of 16B (4 hi k-chunks | 4 lo), slot ^= row&7.

#define BB 8
#define NN 8192
#define MM 2048
#define CF 256
#define CP 256

typedef float f4 __attribute__((ext_vector_type(4)));
typedef short s8v __attribute__((ext_vector_type(8)));

union U4 { uint4 u; s8v s; };

// ---- workspace layout (bytes) ----
#define OFF_IDX    ((size_t)0)                                   // int [B*N][4]
#define OFF_WGT    ((size_t)1 << 20)                             // float [B*N][4]
#define OFF_INTERP ((size_t)2 << 20)                             // float [B][256][N] 64MB
#define OFF_P1S    (OFF_INTERP + (size_t)BB*CF*NN*4)             // float [512][256]
#define OFF_P1Q    (OFF_P1S + (size_t)512*256*4)
#define OFF_P2S    (OFF_P1Q + (size_t)512*256*4)
#define OFF_P2Q    (OFF_P2S + (size_t)512*256*4)
#define OFF_PAR1   (OFF_P2Q + (size_t)512*256*4)                 // float2 [256]
#define OFF_PAR2   (OFF_PAR1 + (size_t)256*8)
#define OFF_WP1    (OFF_PAR2 + (size_t)256*8)                    // 16 slabs x 32KB
#define OFF_WP2    (OFF_WP1 + (size_t)524288)                    // 8 slabs x 32KB

__device__ __forceinline__ f4 relu4(f4 v) {
    v.x = fmaxf(v.x, 0.f); v.y = fmaxf(v.y, 0.f);
    v.z = fmaxf(v.z, 0.f); v.w = fmaxf(v.w, 0.f);
    return v;
}

__device__ __forceinline__ ushort bfrn(float x) {
    unsigned u = __float_as_uint(x);
    return (ushort)((u + 0x7FFFu + ((u >> 16) & 1u)) >> 16);
}
__device__ __forceinline__ void split1(float v, ushort& h, ushort& lo) {
    h = bfrn(v);
    float hf = __uint_as_float(((unsigned)h) << 16);
    lo = bfrn(v - hf);
}
__device__ __forceinline__ uint4 pack8(const ushort* h) {
    uint4 u;
    u.x = (unsigned)h[0] | ((unsigned)h[1] << 16);
    u.y = (unsigned)h[2] | ((unsigned)h[3] << 16);
    u.z = (unsigned)h[4] | ((unsigned)h[5] << 16);
    u.w = (unsigned)h[6] | ((unsigned)h[7] << 16);
    return u;
}

// ---- 1. weight split + pre-swizzle into per-k-step LDS image ----
// Image per k-step: [256 o][8 slots x 16B], slot s at index s^(o&7).
// Slots 0-3 = hi k-chunks (8 bf16 each), 4-7 = lo.
__global__ void k_wsplit(const float* __restrict__ w1, const float* __restrict__ w2,
                         uint4* __restrict__ wp1, uint4* __restrict__ wp2) {
    int i = blockIdx.x * 256 + threadIdx.x;          // 16384 w1 chunks + 8192 w2
    const float* src; uint4* dst; int kt, o, kh, kdim;
    if (i < 16384) { kdim = 512; kt = i >> 10; int r = i & 1023; o = r >> 2; kh = r & 3; src = w1; dst = wp1; }
    else { int j = i - 16384; kdim = 256; kt = j >> 10; int r = j & 1023; o = r >> 2; kh = r & 3; src = w2; dst = wp2; }
    const float* p = src + o * kdim + kt * 32 + kh * 8;
    ushort hh[8], ll[8];
    #pragma unroll
    for (int k = 0; k < 8; ++k) split1(p[k], hh[k], ll[k]);
    uint4* slab = dst + kt * 2048 + o * 8;
    slab[kh ^ (o & 7)] = pack8(hh);
    slab[(kh + 4) ^ (o & 7)] = pack8(ll);
}

// ---- 2. three-NN (unchanged) ----
__device__ __forceinline__ void ins3(float d, int i,
                                     float& d0, int& i0, float& d1, int& i1,
                                     float& d2, int& i2) {
    bool c2 = d < d2, c1 = d < d1, c0 = d < d0;
    d2 = c1 ? d1 : (c2 ? d : d2);  i2 = c1 ? i1 : (c2 ? i : i2);
    d1 = c0 ? d0 : (c1 ? d : d1);  i1 = c0 ? i0 : (c1 ? i : i1);
    d0 = c0 ? d  : d0;             i0 = c0 ? i  : i0;
}

__global__ __launch_bounds__(256) void k_threenn(const float* __restrict__ pc,
                                                 const float* __restrict__ cen,
                                                 int* __restrict__ idx,
                                                 float* __restrict__ wgt) {
    __shared__ f4 c4[MM + 4];
    const int b  = blockIdx.x >> 7;
    const int n0 = (blockIdx.x & 127) << 6;
    const float* cb = cen + b * 3 * MM;
    for (int m = threadIdx.x; m < MM; m += 256) {
        f4 v = {cb[m], cb[MM + m], cb[2 * MM + m], 0.f};
        c4[m + (m >> 9)] = v;
    }
    __syncthreads();
    const int pt  = threadIdx.x >> 2;
    const int sub = threadIdx.x & 3;
    const int n = n0 + pt;
    const float* pb = pc + b * 3 * NN;
    const float px = pb[n], py = pb[NN + n], pz = pb[2 * NN + n];
    float d0 = 3e38f, d1 = 3e38f, d2 = 3e38f;
    int   i0 = 0,    i1 = 0,    i2 = 0;
    const f4* cbase = c4 + sub * 513;
    const int m0 = sub * 512;
    for (int mm = 0; mm < 512; mm += 4) {
        f4 va = cbase[mm], vb = cbase[mm + 1], vc = cbase[mm + 2], vd = cbase[mm + 3];
        float xa = px - va.x, ya = py - va.y, za = pz - va.z;
        float xb2 = px - vb.x, yb2 = py - vb.y, zb2 = pz - vb.z;
        float xc = px - vc.x, yc = py - vc.y, zc = pz - vc.z;
        float xd = px - vd.x, yd = py - vd.y, zd = pz - vd.z;
        float da = fmaf(za, za, fmaf(ya, ya, xa * xa));
        float db = fmaf(zb2, zb2, fmaf(yb2, yb2, xb2 * xb2));
        float dc = fmaf(zc, zc, fmaf(yc, yc, xc * xc));
        float dd = fmaf(zd, zd, fmaf(yd, yd, xd * xd));
        float mn = fminf(fminf(da, db), fminf(dc, dd));
        if (mn < d2) {
            const int mg = m0 + mm;
            ins3(da, mg,     d0, i0, d1, i1, d2, i2);
            ins3(db, mg + 1, d0, i0, d1, i1, d2, i2);
            ins3(dc, mg + 2, d0, i0, d1, i1, d2, i2);
            ins3(dd, mg + 3, d0, i0, d1, i1, d2, i2);
        }
    }
    #pragma unroll
    for (int m = 1; m <= 2; m <<= 1) {
        float e0 = __shfl_xor(d0, m), e1 = __shfl_xor(d1, m), e2 = __shfl_xor(d2, m);
        int   j0 = __shfl_xor(i0, m), j1 = __shfl_xor(i1, m), j2 = __shfl_xor(i2, m);
        ins3(e0, j0, d0, i0, d1, i1, d2, i2);
        ins3(e1, j1, d0, i0, d1, i1, d2, i2);
        ins3(e2, j2, d0, i0, d1, i1, d2, i2);
    }
    if (sub == 0) {
        float w0 = 1.f / (d0 + 1e-8f), w1 = 1.f / (d1 + 1e-8f), w2 = 1.f / (d2 + 1e-8f);
        float inv = 1.f / (w0 + w1 + w2);
        const int p = b * NN + n;
        *(int4*)(idx + p * 4) = make_int4(i0, i1, i2, 0);
        f4 wv = {w0 * inv, w1 * inv, w2 * inv, 0.f};
        *(f4*)(wgt + p * 4) = wv;
    }
}

// ---- 3. gather-interpolate (unchanged) ----
__global__ __launch_bounds__(256) void k_interp(const float* __restrict__ cf,
                                                const int* __restrict__ idx,
                                                const float* __restrict__ wgt,
                                                float* __restrict__ itp) {
    const int b  = blockIdx.x >> 7;
    const int n0 = (blockIdx.x & 127) << 6;
    const int pp = threadIdx.x & 63;
    const int cq = threadIdx.x >> 6;
    const int p = b * NN + n0 + pp;
    const int4 iv = *(const int4*)(idx + p * 4);
    const f4   wv = *(const f4*)(wgt + p * 4);
    const float* cb = cf + b * CF * MM;
    float* op = itp + b * CF * NN + n0 + pp;
    #pragma unroll 2
    for (int cc = 0; cc < 64; ++cc) {
        const int c = cq * 64 + cc;
        const float* row = cb + c * MM;
        op[c * NN] = row[iv.x] * wv.x + row[iv.y] * wv.y + row[iv.z] * wv.z;
    }
}

// ---- 4/6. split-bf16 MFMA GEMM ----
// KDIM=512: X = [xa(c<256); xb(c>=256)]. KDIM=256: X = xa with BN+relu (BNIN).
template<int KDIM, bool BNIN>
__global__ __launch_bounds__(256, 2) void k_gemm(const float* xa,
                                                 const float* __restrict__ xb,
                                                 const uint4* __restrict__ wp,
                                                 float* yo,
                                                 const float2* __restrict__ par,
                                                 float* __restrict__ ps,
                                                 float* __restrict__ pq) {
    __shared__ __align__(16) unsigned char lds[49152];   // X 16KB | W 32KB
    const int tid = threadIdx.x;
    const int b  = blockIdx.x >> 6;
    const int n0 = (blockIdx.x & 63) << 7;
    const int nl = tid & 127;                 // staged column
    const int kq = (tid >> 7) << 4;           // staged rows kq..kq+15
    const int l = tid & 63, w = tid >> 6;
    const int lr = l & 15, lk = l >> 4;
    const int sw = (nl & 7) << 4;
    const int h0 = kq >> 3;                   // hi slot base: 0 or 2

    f4 acc[4][8];
    #pragma unroll
    for (int mo = 0; mo < 4; ++mo)
        #pragma unroll
        for (int nn = 0; nn < 8; ++nn) acc[mo][nn] = (f4){0.f, 0.f, 0.f, 0.f};

    float xp[16];
    {   // prologue: load k-step 0
        const float* s = (KDIM == 512 && kq >= 256) ? xb : xa;  // kq<256 always; keeps form
        s = xa + ((size_t)b * 256 + kq) * NN + n0 + nl;
        #pragma unroll
        for (int i = 0; i < 16; ++i) xp[i] = s[i * NN];
    }

    for (int kt = 0; kt < KDIM / 32; ++kt) {
        const int c0 = kt * 32 + kq;
        __syncthreads();                      // prev compute done; xp arrived
        {   // convert + swizzled LDS write
            ushort hh[16], ll[16];
            #pragma unroll
            for (int i = 0; i < 16; ++i) {
                float v = xp[i];
                if constexpr (BNIN) {
                    float2 pr = par[c0 + i];
                    v = fmaxf(fmaf(v, pr.x, pr.y), 0.f);
                }
                split1(v, hh[i], ll[i]);
            }
            const int xrow = nl << 7;
            *(uint4*)(lds + xrow + (((h0    ) << 4) ^ sw)) = pack8(hh);
            *(uint4*)(lds + xrow + (((h0 + 1) << 4) ^ sw)) = pack8(hh + 8);
            *(uint4*)(lds + xrow + (((h0 + 4) << 4) ^ sw)) = pack8(ll);
            *(uint4*)(lds + xrow + (((h0 + 5) << 4) ^ sw)) = pack8(ll + 8);
        }
        {   // W stage: linear copy of pre-swizzled slab (32KB)
            const uint4* wsrc = wp + kt * 2048 + tid;
            #pragma unroll
            for (int c = 0; c < 8; ++c) {
                uint4 v = wsrc[c * 256];
                *(uint4*)(lds + 16384 + c * 4096 + tid * 16) = v;
            }
        }
        __syncthreads();                      // tile ready
        if (kt + 1 < KDIM / 32) {             // prefetch next X (hides under MFMA)
            const int c1 = (kt + 1) * 32 + kq;
            const float* s = (KDIM == 512 && c1 >= 256)
                ? xb + ((size_t)b * 256 + (c1 - 256)) * NN + n0 + nl
                : xa + ((size_t)b * 256 + c1) * NN + n0 + nl;
            #pragma unroll
            for (int i = 0; i < 16; ++i) xp[i] = s[i * NN];
        }
        // A fragments (W)
        U4 Ah[4], Al[4];
        #pragma unroll
        for (int mo = 0; mo < 4; ++mo) {
            const int o = w * 64 + mo * 16 + lr;
            const unsigned char* r = lds + 16384 + o * 128;
            const int osw = (o & 7) << 4;
            Ah[mo].u = *(const uint4*)(r + ((lk << 4) ^ osw));
            Al[mo].u = *(const uint4*)(r + ((64 + (lk << 4)) ^ osw));
        }
        // B fragments (X) + 3-product MFMA
        #pragma unroll
        for (int nn = 0; nn < 8; ++nn) {
            const int n = nn * 16 + lr;
            const unsigned char* r = lds + n * 128;
            const int nsw = (n & 7) << 4;
            U4 Bh, Bl;
            Bh.u = *(const uint4*)(r + ((lk << 4) ^ nsw));
            Bl.u = *(const uint4*)(r + ((64 + (lk << 4)) ^ nsw));
            #pragma unroll
            for (int mo = 0; mo < 4; ++mo)
                acc[mo][nn] = __builtin_amdgcn_mfma_f32_16x16x32_bf16(Ah[mo].s, Bh.s, acc[mo][nn], 0, 0, 0);
            #pragma unroll
            for (int mo = 0; mo < 4; ++mo)
                acc[mo][nn] = __builtin_amdgcn_mfma_f32_16x16x32_bf16(Al[mo].s, Bh.s, acc[mo][nn], 0, 0, 0);
            #pragma unroll
            for (int mo = 0; mo < 4; ++mo)
                acc[mo][nn] = __builtin_amdgcn_mfma_f32_16x16x32_bf16(Ah[mo].s, Bl.s, acc[mo][nn], 0, 0, 0);
        }
    }

    // ---- epilogue: BN partials + y store ----
    // D layout: col = lr (n), row = lk*4 + j (o within frag)
    float sv[4][4], qv[4][4];
    #pragma unroll
    for (int mo = 0; mo < 4; ++mo)
        #pragma unroll
        for (int j = 0; j < 4; ++j) { sv[mo][j] = 0.f; qv[mo][j] = 0.f; }
    #pragma unroll
    for (int mo = 0; mo < 4; ++mo)
        #pragma unroll
        for (int nn = 0; nn < 8; ++nn)
            #pragma unroll
            for (int j = 0; j < 4; ++j) {
                float a = acc[mo][nn][j];
                sv[mo][j] += a; qv[mo][j] += a * a;
            }
    #pragma unroll
    for (int m = 1; m < 16; m <<= 1)
        #pragma unroll
        for (int mo = 0; mo < 4; ++mo)
            #pragma unroll
            for (int j = 0; j < 4; ++j) {
                sv[mo][j] += __shfl_xor(sv[mo][j], m, 64);
                qv[mo][j] += __shfl_xor(qv[mo][j], m, 64);
            }
    if (lr == 0) {
        #pragma unroll
        for (int mo = 0; mo < 4; ++mo) {
            const int o0 = w * 64 + mo * 16 + lk * 4;
            f4 vs = {sv[mo][0], sv[mo][1], sv[mo][2], sv[mo][3]};
            f4 vq = {qv[mo][0], qv[mo][1], qv[mo][2], qv[mo][3]};
            *(f4*)(ps + blockIdx.x * 256 + o0) = vs;
            *(f4*)(pq + blockIdx.x * 256 + o0) = vq;
        }
    }
    float* yb = yo + (size_t)b * 256 * NN + n0;
    #pragma unroll
    for (int mo = 0; mo < 4; ++mo)
        #pragma unroll
        for (int j = 0; j < 4; ++j) {
            float* row = yb + (size_t)(w * 64 + mo * 16 + lk * 4 + j) * NN + lr;
            #pragma unroll
            for (int nn = 0; nn < 8; ++nn) row[nn * 16] = acc[mo][nn][j];
        }
}

// ---- 5/7. BN stats -> (scale, shift) ----
__global__ void k_params(const float* __restrict__ ps, const float* __restrict__ pq,
                         const float* __restrict__ gamma, const float* __restrict__ beta,
                         float2* __restrict__ out) {
    __shared__ float rs[256], rq[256];
    const int oo = threadIdx.x & 15, seg = threadIdx.x >> 4;
    const int o = blockIdx.x * 16 + oo;
    float s = 0.f, q = 0.f;
    for (int blk = seg; blk < 512; blk += 16) {
        s += ps[blk * 256 + o];
        q += pq[blk * 256 + o];
    }
    rs[threadIdx.x] = s; rq[threadIdx.x] = q;
    __syncthreads();
    if (seg == 0) {
        float S = 0.f, Q = 0.f;
        #pragma unroll
        for (int g = 0; g < 16; ++g) { S += rs[g * 16 + oo]; Q += rq[g * 16 + oo]; }
        float mean = S * (1.f / 65536.f);
        float var  = Q * (1.f / 65536.f) - mean * mean;
        float rstd = rsqrtf(var + 1e-5f);
        float sc = gamma[o] * rstd;
        out[o] = make_float2(sc, beta[o] - mean * sc);
    }
}

// ---- 8. final in-place BN+relu ----
__global__ __launch_bounds__(256) void k_final(float* __restrict__ yy,
                                               const float2* __restrict__ par) {
    int i = blockIdx.x * 256 + threadIdx.x;
    #pragma unroll 4
    for (int t = i; t < 4194304; t += 524288) {
        f4 v = ((f4*)yy)[t];
        float2 pr = par[(t >> 11) & 255];
        v = relu4(v * pr.x + pr.y);
        ((f4*)yy)[t] = v;
    }
}

extern "C" void kernel_launch(void* const* d_in, const int* in_sizes, int n_in,
                              void* d_out, int out_size, void* d_ws, size_t ws_size,
                              hipStream_t stream) {
    const float* pc  = (const float*)d_in[0];
    const float* cen = (const float*)d_in[1];
    const float* cf  = (const float*)d_in[2];
    const float* pf  = (const float*)d_in[3];
    const float* w1  = (const float*)d_in[4];
    const float* g1  = (const float*)d_in[6];
    const float* be1 = (const float*)d_in[7];
    const float* w2  = (const float*)d_in[8];
    const float* g2  = (const float*)d_in[10];
    const float* be2 = (const float*)d_in[11];

    char* ws = (char*)d_ws;
    int*    idx  = (int*)  (ws + OFF_IDX);
    float*  wgt  = (float*)(ws + OFF_WGT);
    float*  itp  = (float*)(ws + OFF_INTERP);
    float*  p1s  = (float*)(ws + OFF_P1S);
    float*  p1q  = (float*)(ws + OFF_P1Q);
    float*  p2s  = (float*)(ws + OFF_P2S);
    float*  p2q  = (float*)(ws + OFF_P2Q);
    float2* par1 = (float2*)(ws + OFF_PAR1);
    float2* par2 = (float2*)(ws + OFF_PAR2);
    uint4*  wp1  = (uint4*)(ws + OFF_WP1);
    uint4*  wp2  = (uint4*)(ws + OFF_WP2);
    float*  out  = (float*)d_out;

    k_wsplit<<<96, 256, 0, stream>>>(w1, w2, wp1, wp2);
    k_threenn<<<1024, 256, 0, stream>>>(pc, cen, idx, wgt);
    k_interp<<<1024, 256, 0, stream>>>(cf, idx, wgt, itp);
    k_gemm<512, false><<<512, 256, 0, stream>>>(itp, pf, wp1, out, par1, p1s, p1q);
    k_params<<<16, 256, 0, stream>>>(p1s, p1q, g1, be1, par1);
    k_gemm<256, true><<<512, 256, 0, stream>>>(out, out, wp2, out, par1, p2s, p2q);
    k_params<<<16, 256, 0, stream>>>(p2s, p2q, g2, be2, par2);
    k_final<<<2048, 256, 0, stream>>>(out, par2);
    (void)hipMemcpyAsync(out + 16777216, pc, (size_t)BB * 3 * NN * 4,
                         hipMemcpyDeviceToDevice, stream);
}

// Round 5
// 235.384 us; speedup vs baseline: 2.7178x; 1.2273x over previous
//
#include <hip/hip_runtime.h>

// PointNetFP: three_nn_interpolate -> concat -> conv_bn_relu x2 (training-mode BN)
// B=8, N=8192, M=2048, C=256, C2=256, O1=O2=256.
//
// Pipeline:
//  1. k_wsplit  : split w1/w2 into bf16 hi/lo, pre-swizzled per-32k-step LDS image
//  2. k_threenn : per-point top-3 nearest centers (4 thr/point + shfl merge)
//  3. k_interp  : LDS-staged gather -> interp [B][256][N] f32 (ws); blocks own 8 channels
//  4. k_gemm<512,false>: y1 = w1 @ [interp;pf] via split-bf16 MFMA (3 products)
//                        -> d_out raw + per-block BN partials
//  5. k_params  : BN1 stats -> (scale, shift)   (conv bias cancels under BN)
//  6. k_gemm<256,true> : x1 = relu(BN(y1)) in staging; y2 = w2 @ x1 IN-PLACE on d_out
//  7. k_params  : BN2 stats
//  8. k_final   : in-place relu(y2*sc+sh)
//  9. memcpyAsync: points_coords -> tail of d_out
//
// GEMM geometry: block [O=256][n=128], wave [64 o][128 n] = 4x8 16x16x32 frags,
// acc 128 VGPR. Split MFMA: acc += Ah*Bh + Al*Bh + Ah*Bl (lo*lo ~2^-18 dropped).
// LDS image rows = 128B = 8 slots of 16B (4 hi k-chunks | 4 lo), slot ^= row&7.

#define BB 8
#define NN 8192
#define MM 2048
#define CF 256
#define CP 256

typedef float f4 __attribute__((ext_vector_type(4)));
typedef short s8v __attribute__((ext_vector_type(8)));

union U4 { uint4 u; s8v s; };

// ---- workspace layout (bytes) ----
#define OFF_IDX    ((size_t)0)                                   // int [B*N][4]
#define OFF_WGT    ((size_t)1 << 20)                             // float [B*N][4]
#define OFF_INTERP ((size_t)2 << 20)                             // float [B][256][N] 64MB
#define OFF_P1S    (OFF_INTERP + (size_t)BB*CF*NN*4)             // float [512][256]
#define OFF_P1Q    (OFF_P1S + (size_t)512*256*4)
#define OFF_P2S    (OFF_P1Q + (size_t)512*256*4)
#define OFF_P2Q    (OFF_P2S + (size_t)512*256*4)
#define OFF_PAR1   (OFF_P2Q + (size_t)512*256*4)                 // float2 [256]
#define OFF_PAR2   (OFF_PAR1 + (size_t)256*8)
#define OFF_WP1    (OFF_PAR2 + (size_t)256*8)                    // 16 slabs x 32KB
#define OFF_WP2    (OFF_WP1 + (size_t)524288)                    // 8 slabs x 32KB

__device__ __forceinline__ f4 relu4(f4 v) {
    v.x = fmaxf(v.x, 0.f); v.y = fmaxf(v.y, 0.f);
    v.z = fmaxf(v.z, 0.f); v.w = fmaxf(v.w, 0.f);
    return v;
}

__device__ __forceinline__ ushort bfrn(float x) {
    unsigned u = __float_as_uint(x);
    return (ushort)((u + 0x7FFFu + ((u >> 16) & 1u)) >> 16);
}
__device__ __forceinline__ void split1(float v, ushort& h, ushort& lo) {
    h = bfrn(v);
    float hf = __uint_as_float(((unsigned)h) << 16);
    lo = bfrn(v - hf);
}
__device__ __forceinline__ uint4 pack8(const ushort* h) {
    uint4 u;
    u.x = (unsigned)h[0] | ((unsigned)h[1] << 16);
    u.y = (unsigned)h[2] | ((unsigned)h[3] << 16);
    u.z = (unsigned)h[4] | ((unsigned)h[5] << 16);
    u.w = (unsigned)h[6] | ((unsigned)h[7] << 16);
    return u;
}

// ---- 1. weight split + pre-swizzle into per-k-step LDS image ----
__global__ void k_wsplit(const float* __restrict__ w1, const float* __restrict__ w2,
                         uint4* __restrict__ wp1, uint4* __restrict__ wp2) {
    int i = blockIdx.x * 256 + threadIdx.x;          // 16384 w1 chunks + 8192 w2
    const float* src; uint4* dst; int kt, o, kh, kdim;
    if (i < 16384) { kdim = 512; kt = i >> 10; int r = i & 1023; o = r >> 2; kh = r & 3; src = w1; dst = wp1; }
    else { int j = i - 16384; kdim = 256; kt = j >> 10; int r = j & 1023; o = r >> 2; kh = r & 3; src = w2; dst = wp2; }
    const float* p = src + o * kdim + kt * 32 + kh * 8;
    ushort hh[8], ll[8];
    #pragma unroll
    for (int k = 0; k < 8; ++k) split1(p[k], hh[k], ll[k]);
    uint4* slab = dst + kt * 2048 + o * 8;
    slab[kh ^ (o & 7)] = pack8(hh);
    slab[(kh + 4) ^ (o & 7)] = pack8(ll);
}

// ---- 2. three-NN ----
__device__ __forceinline__ void ins3(float d, int i,
                                     float& d0, int& i0, float& d1, int& i1,
                                     float& d2, int& i2) {
    bool c2 = d < d2, c1 = d < d1, c0 = d < d0;
    d2 = c1 ? d1 : (c2 ? d : d2);  i2 = c1 ? i1 : (c2 ? i : i2);
    d1 = c0 ? d0 : (c1 ? d : d1);  i1 = c0 ? i0 : (c1 ? i : i1);
    d0 = c0 ? d  : d0;             i0 = c0 ? i  : i0;
}

__global__ __launch_bounds__(256) void k_threenn(const float* __restrict__ pc,
                                                 const float* __restrict__ cen,
                                                 int* __restrict__ idx,
                                                 float* __restrict__ wgt) {
    __shared__ f4 c4[MM + 4];
    const int b  = blockIdx.x >> 7;
    const int n0 = (blockIdx.x & 127) << 6;
    const float* cb = cen + b * 3 * MM;
    for (int m = threadIdx.x; m < MM; m += 256) {
        f4 v = {cb[m], cb[MM + m], cb[2 * MM + m], 0.f};
        c4[m + (m >> 9)] = v;
    }
    __syncthreads();
    const int pt  = threadIdx.x >> 2;
    const int sub = threadIdx.x & 3;
    const int n = n0 + pt;
    const float* pb = pc + b * 3 * NN;
    const float px = pb[n], py = pb[NN + n], pz = pb[2 * NN + n];
    float d0 = 3e38f, d1 = 3e38f, d2 = 3e38f;
    int   i0 = 0,    i1 = 0,    i2 = 0;
    const f4* cbase = c4 + sub * 513;
    const int m0 = sub * 512;
    for (int mm = 0; mm < 512; mm += 4) {
        f4 va = cbase[mm], vb = cbase[mm + 1], vc = cbase[mm + 2], vd = cbase[mm + 3];
        float xa = px - va.x, ya = py - va.y, za = pz - va.z;
        float xb2 = px - vb.x, yb2 = py - vb.y, zb2 = pz - vb.z;
        float xc = px - vc.x, yc = py - vc.y, zc = pz - vc.z;
        float xd = px - vd.x, yd = py - vd.y, zd = pz - vd.z;
        float da = fmaf(za, za, fmaf(ya, ya, xa * xa));
        float db = fmaf(zb2, zb2, fmaf(yb2, yb2, xb2 * xb2));
        float dc = fmaf(zc, zc, fmaf(yc, yc, xc * xc));
        float dd = fmaf(zd, zd, fmaf(yd, yd, xd * xd));
        float mn = fminf(fminf(da, db), fminf(dc, dd));
        if (mn < d2) {
            const int mg = m0 + mm;
            ins3(da, mg,     d0, i0, d1, i1, d2, i2);
            ins3(db, mg + 1, d0, i0, d1, i1, d2, i2);
            ins3(dc, mg + 2, d0, i0, d1, i1, d2, i2);
            ins3(dd, mg + 3, d0, i0, d1, i1, d2, i2);
        }
    }
    #pragma unroll
    for (int m = 1; m <= 2; m <<= 1) {
        float e0 = __shfl_xor(d0, m), e1 = __shfl_xor(d1, m), e2 = __shfl_xor(d2, m);
        int   j0 = __shfl_xor(i0, m), j1 = __shfl_xor(i1, m), j2 = __shfl_xor(i2, m);
        ins3(e0, j0, d0, i0, d1, i1, d2, i2);
        ins3(e1, j1, d0, i0, d1, i1, d2, i2);
        ins3(e2, j2, d0, i0, d1, i1, d2, i2);
    }
    if (sub == 0) {
        float w0 = 1.f / (d0 + 1e-8f), w1 = 1.f / (d1 + 1e-8f), w2 = 1.f / (d2 + 1e-8f);
        float inv = 1.f / (w0 + w1 + w2);
        const int p = b * NN + n;
        *(int4*)(idx + p * 4) = make_int4(i0, i1, i2, 0);
        f4 wv = {w0 * inv, w1 * inv, w2 * inv, 0.f};
        *(f4*)(wgt + p * 4) = wv;
    }
}

// ---- 3. gather-interpolate, LDS-staged ----
// Block = (b, cg of 8 channels, n-half). Stage 8 cf rows pair-packed as float2
// (64 KB LDS); stream 4096 points with coalesced idx/wgt reads, LDS gathers,
// coalesced stores. cf is read exactly once across the grid; idx/wgt re-reads
// stay L2-resident (128 KB live set per (b,nh)).
__global__ __launch_bounds__(512) void k_interp(const float* __restrict__ cf,
                                                const int* __restrict__ idx,
                                                const float* __restrict__ wgt,
                                                float* __restrict__ itp) {
    __shared__ float2 l2[4][MM];                     // 8 rows pair-packed: 64 KB
    const int blk = blockIdx.x;
    const int b  = blk >> 6;                         // 64 blocks/batch: 32 cg x 2 nh
    const int cg = (blk >> 1) & 31;
    const int nh = blk & 1;
    const int tid = threadIdx.x;
    const float* cbase = cf + ((size_t)b * CF + cg * 8) * MM;
    #pragma unroll
    for (int q = 0; q < 4; ++q) {                    // stage rows 2q, 2q+1 interleaved
        f4 ae = *(const f4*)(cbase + (2 * q) * MM + tid * 4);
        f4 ao = *(const f4*)(cbase + (2 * q + 1) * MM + tid * 4);
        #pragma unroll
        for (int i = 0; i < 4; ++i) l2[q][tid * 4 + i] = make_float2(ae[i], ao[i]);
    }
    __syncthreads();
    const int nb = nh * 4096;
    float* op = itp + ((size_t)b * CF + cg * 8) * NN + nb;
    #pragma unroll 2
    for (int it = 0; it < 8; ++it) {
        const int nn = it * 512 + tid;
        const int p = b * NN + nb + nn;
        const int4 iv = *(const int4*)(idx + p * 4);
        const f4   wv = *(const f4*)(wgt + p * 4);
        #pragma unroll
        for (int q = 0; q < 4; ++q) {
            float2 v0 = l2[q][iv.x], v1 = l2[q][iv.y], v2 = l2[q][iv.z];
            float sx = fmaf(v0.x, wv.x, fmaf(v1.x, wv.y, v2.x * wv.z));
            float sy = fmaf(v0.y, wv.x, fmaf(v1.y, wv.y, v2.y * wv.z));
            op[(size_t)(2 * q) * NN + nn]     = sx;
            op[(size_t)(2 * q + 1) * NN + nn] = sy;
        }
    }
}

// ---- 4/6. split-bf16 MFMA GEMM ----
template<int KDIM, bool BNIN>
__global__ __launch_bounds__(256, 2) void k_gemm(const float* xa,
                                                 const float* __restrict__ xb,
                                                 const uint4* __restrict__ wp,
                                                 float* yo,
                                                 const float2* __restrict__ par,
                                                 float* __restrict__ ps,
                                                 float* __restrict__ pq) {
    __shared__ __align__(16) unsigned char lds[49152];   // X 16KB | W 32KB
    const int tid = threadIdx.x;
    const int b  = blockIdx.x >> 6;
    const int n0 = (blockIdx.x & 63) << 7;
    const int nl = tid & 127;
    const int kq = (tid >> 7) << 4;
    const int l = tid & 63, w = tid >> 6;
    const int lr = l & 15, lk = l >> 4;
    const int sw = (nl & 7) << 4;
    const int h0 = kq >> 3;

    f4 acc[4][8];
    #pragma unroll
    for (int mo = 0; mo < 4; ++mo)
        #pragma unroll
        for (int nn = 0; nn < 8; ++nn) acc[mo][nn] = (f4){0.f, 0.f, 0.f, 0.f};

    float xp[16];
    {
        const float* s = xa + ((size_t)b * 256 + kq) * NN + n0 + nl;
        #pragma unroll
        for (int i = 0; i < 16; ++i) xp[i] = s[i * NN];
    }

    for (int kt = 0; kt < KDIM / 32; ++kt) {
        const int c0 = kt * 32 + kq;
        __syncthreads();
        {
            ushort hh[16], ll[16];
            #pragma unroll
            for (int i = 0; i < 16; ++i) {
                float v = xp[i];
                if constexpr (BNIN) {
                    float2 pr = par[c0 + i];
                    v = fmaxf(fmaf(v, pr.x, pr.y), 0.f);
                }
                split1(v, hh[i], ll[i]);
            }
            const int xrow = nl << 7;
            *(uint4*)(lds + xrow + (((h0    ) << 4) ^ sw)) = pack8(hh);
            *(uint4*)(lds + xrow + (((h0 + 1) << 4) ^ sw)) = pack8(hh + 8);
            *(uint4*)(lds + xrow + (((h0 + 4) << 4) ^ sw)) = pack8(ll);
            *(uint4*)(lds + xrow + (((h0 + 5) << 4) ^ sw)) = pack8(ll + 8);
        }
        {
            const uint4* wsrc = wp + kt * 2048 + tid;
            #pragma unroll
            for (int c = 0; c < 8; ++c) {
                uint4 v = wsrc[c * 256];
                *(uint4*)(lds + 16384 + c * 4096 + tid * 16) = v;
            }
        }
        __syncthreads();
        if (kt + 1 < KDIM / 32) {
            const int c1 = (kt + 1) * 32 + kq;
            const float* s = (KDIM == 512 && c1 >= 256)
                ? xb + ((size_t)b * 256 + (c1 - 256)) * NN + n0 + nl
                : xa + ((size_t)b * 256 + c1) * NN + n0 + nl;
            #pragma unroll
            for (int i = 0; i < 16; ++i) xp[i] = s[i * NN];
        }
        U4 Ah[4], Al[4];
        #pragma unroll
        for (int mo = 0; mo < 4; ++mo) {
            const int o = w * 64 + mo * 16 + lr;
            const unsigned char* r = lds + 16384 + o * 128;
            const int osw = (o & 7) << 4;
            Ah[mo].u = *(const uint4*)(r + ((lk << 4) ^ osw));
            Al[mo].u = *(const uint4*)(r + ((64 + (lk << 4)) ^ osw));
        }
        #pragma unroll
        for (int nn = 0; nn < 8; ++nn) {
            const int n = nn * 16 + lr;
            const unsigned char* r = lds + n * 128;
            const int nsw = (n & 7) << 4;
            U4 Bh, Bl;
            Bh.u = *(const uint4*)(r + ((lk << 4) ^ nsw));
            Bl.u = *(const uint4*)(r + ((64 + (lk << 4)) ^ nsw));
            #pragma unroll
            for (int mo = 0; mo < 4; ++mo)
                acc[mo][nn] = __builtin_amdgcn_mfma_f32_16x16x32_bf16(Ah[mo].s, Bh.s, acc[mo][nn], 0, 0, 0);
            #pragma unroll
            for (int mo = 0; mo < 4; ++mo)
                acc[mo][nn] = __builtin_amdgcn_mfma_f32_16x16x32_bf16(Al[mo].s, Bh.s, acc[mo][nn], 0, 0, 0);
            #pragma unroll
            for (int mo = 0; mo < 4; ++mo)
                acc[mo][nn] = __builtin_amdgcn_mfma_f32_16x16x32_bf16(Ah[mo].s, Bl.s, acc[mo][nn], 0, 0, 0);
        }
    }

    float sv[4][4], qv[4][4];
    #pragma unroll
    for (int mo = 0; mo < 4; ++mo)
        #pragma unroll
        for (int j = 0; j < 4; ++j) { sv[mo][j] = 0.f; qv[mo][j] = 0.f; }
    #pragma unroll
    for (int mo = 0; mo < 4; ++mo)
        #pragma unroll
        for (int nn = 0; nn < 8; ++nn)
            #pragma unroll
            for (int j = 0; j < 4; ++j) {
                float a = acc[mo][nn][j];
                sv[mo][j] += a; qv[mo][j] += a * a;
            }
    #pragma unroll
    for (int m = 1; m < 16; m <<= 1)
        #pragma unroll
        for (int mo = 0; mo < 4; ++mo)
            #pragma unroll
            for (int j = 0; j < 4; ++j) {
                sv[mo][j] += __shfl_xor(sv[mo][j], m, 64);
                qv[mo][j] += __shfl_xor(qv[mo][j], m, 64);
            }
    if (lr == 0) {
        #pragma unroll
        for (int mo = 0; mo < 4; ++mo) {
            const int o0 = w * 64 + mo * 16 + lk * 4;
            f4 vs = {sv[mo][0], sv[mo][1], sv[mo][2], sv[mo][3]};
            f4 vq = {qv[mo][0], qv[mo][1], qv[mo][2], qv[mo][3]};
            *(f4*)(ps + blockIdx.x * 256 + o0) = vs;
            *(f4*)(pq + blockIdx.x * 256 + o0) = vq;
        }
    }
    float* yb = yo + (size_t)b * 256 * NN + n0;
    #pragma unroll
    for (int mo = 0; mo < 4; ++mo)
        #pragma unroll
        for (int j = 0; j < 4; ++j) {
            float* row = yb + (size_t)(w * 64 + mo * 16 + lk * 4 + j) * NN + lr;
            #pragma unroll
            for (int nn = 0; nn < 8; ++nn) row[nn * 16] = acc[mo][nn][j];
        }
}

// ---- 5/7. BN stats -> (scale, shift) ----
__global__ void k_params(const float* __restrict__ ps, const float* __restrict__ pq,
                         const float* __restrict__ gamma, const float* __restrict__ beta,
                         float2* __restrict__ out) {
    __shared__ float rs[256], rq[256];
    const int oo = threadIdx.x & 15, seg = threadIdx.x >> 4;
    const int o = blockIdx.x * 16 + oo;
    float s = 0.f, q = 0.f;
    for (int blk = seg; blk < 512; blk += 16) {
        s += ps[blk * 256 + o];
        q += pq[blk * 256 + o];
    }
    rs[threadIdx.x] = s; rq[threadIdx.x] = q;
    __syncthreads();
    if (seg == 0) {
        float S = 0.f, Q = 0.f;
        #pragma unroll
        for (int g = 0; g < 16; ++g) { S += rs[g * 16 + oo]; Q += rq[g * 16 + oo]; }
        float mean = S * (1.f / 65536.f);
        float var  = Q * (1.f / 65536.f) - mean * mean;
        float rstd = rsqrtf(var + 1e-5f);
        float sc = gamma[o] * rstd;
        out[o] = make_float2(sc, beta[o] - mean * sc);
    }
}

// ---- 8. final in-place BN+relu ----
__global__ __launch_bounds__(256) void k_final(float* __restrict__ yy,
                                               const float2* __restrict__ par) {
    int i = blockIdx.x * 256 + threadIdx.x;
    #pragma unroll 4
    for (int t = i; t < 4194304; t += 524288) {
        f4 v = ((f4*)yy)[t];
        float2 pr = par[(t >> 11) & 255];
        v = relu4(v * pr.x + pr.y);
        ((f4*)yy)[t] = v;
    }
}

extern "C" void kernel_launch(void* const* d_in, const int* in_sizes, int n_in,
                              void* d_out, int out_size, void* d_ws, size_t ws_size,
                              hipStream_t stream) {
    const float* pc  = (const float*)d_in[0];
    const float* cen = (const float*)d_in[1];
    const float* cf  = (const float*)d_in[2];
    const float* pf  = (const float*)d_in[3];
    const float* w1  = (const float*)d_in[4];
    const float* g1  = (const float*)d_in[6];
    const float* be1 = (const float*)d_in[7];
    const float* w2  = (const float*)d_in[8];
    const float* g2  = (const float*)d_in[10];
    const float* be2 = (const float*)d_in[11];

    char* ws = (char*)d_ws;
    int*    idx  = (int*)  (ws + OFF_IDX);
    float*  wgt  = (float*)(ws + OFF_WGT);
    float*  itp  = (float*)(ws + OFF_INTERP);
    float*  p1s  = (float*)(ws + OFF_P1S);
    float*  p1q  = (float*)(ws + OFF_P1Q);
    float*  p2s  = (float*)(ws + OFF_P2S);
    float*  p2q  = (float*)(ws + OFF_P2Q);
    float2* par1 = (float2*)(ws + OFF_PAR1);
    float2* par2 = (float2*)(ws + OFF_PAR2);
    uint4*  wp1  = (uint4*)(ws + OFF_WP1);
    uint4*  wp2  = (uint4*)(ws + OFF_WP2);
    float*  out  = (float*)d_out;

    k_wsplit<<<96, 256, 0, stream>>>(w1, w2, wp1, wp2);
    k_threenn<<<1024, 256, 0, stream>>>(pc, cen, idx, wgt);
    k_interp<<<512, 512, 0, stream>>>(cf, idx, wgt, itp);
    k_gemm<512, false><<<512, 256, 0, stream>>>(itp, pf, wp1, out, par1, p1s, p1q);
    k_params<<<16, 256, 0, stream>>>(p1s, p1q, g1, be1, par1);
    k_gemm<256, true><<<512, 256, 0, stream>>>(out, out, wp2, out, par1, p2s, p2q);
    k_params<<<16, 256, 0, stream>>>(p2s, p2q, g2, be2, par2);
    k_final<<<2048, 256, 0, stream>>>(out, par2);
    (void)hipMemcpyAsync(out + 16777216, pc, (size_t)BB * 3 * NN * 4,
                         hipMemcpyDeviceToDevice, stream);
}

// Round 6
// 230.567 us; speedup vs baseline: 2.7746x; 1.0209x over previous
//
#include <hip/hip_runtime.h>

// PointNetFP: three_nn_interpolate -> concat -> conv_bn_relu x2 (training-mode BN)
// B=8, N=8192, M=2048, C=256, C2=256, O1=O2=256.
//
// Pipeline:
//  1. k_wsplit  : split w1/w2 into bf16 hi/lo, pre-swizzled per-32k-step LDS image
//  2. k_threenn : per-point top-3 nearest centers (4 thr/point, BRANCHLESS insert)
//  3. k_interp  : LDS-staged gather -> interp [B][256][N] f32 (ws); blocks own 8 channels
//  4. k_gemm<512,false>: y1 = w1 @ [interp;pf] via split-bf16 MFMA (3 products)
//                        -> d_out raw + per-block BN partials
//  5. k_params  : BN1 stats -> (scale, shift)   (conv bias cancels under BN)
//  6. k_gemm<256,true> : x1 = relu(BN(y1)) in staging; y2 = w2 @ x1 IN-PLACE on d_out
//  7. k_params  : BN2 stats
//  8. k_final   : in-place relu(y2*sc+sh)
//  9. memcpyAsync: points_coords -> tail of d_out
//
// GEMM geometry: block [O=256][n=128], wave [64 o][128 n] = 4x8 16x16x32 frags,
// acc 128 VGPR. Split MFMA: acc += Ah*Bh + Al*Bh + Ah*Bl (lo*lo ~2^-18 dropped).
// LDS image rows = 128B = 8 slots of 16B (4 hi k-chunks | 4 lo), slot ^= row&7.

#define BB 8
#define NN 8192
#define MM 2048
#define CF 256
#define CP 256

typedef float f4 __attribute__((ext_vector_type(4)));
typedef short s8v __attribute__((ext_vector_type(8)));

union U4 { uint4 u; s8v s; };

// ---- workspace layout (bytes) ----
#define OFF_IDX    ((size_t)0)                                   // int [B*N][4]
#define OFF_WGT    ((size_t)1 << 20)                             // float [B*N][4]
#define OFF_INTERP ((size_t)2 << 20)                             // float [B][256][N] 64MB
#define OFF_P1S    (OFF_INTERP + (size_t)BB*CF*NN*4)             // float [512][256]
#define OFF_P1Q    (OFF_P1S + (size_t)512*256*4)
#define OFF_P2S    (OFF_P1Q + (size_t)512*256*4)
#define OFF_P2Q    (OFF_P2S + (size_t)512*256*4)
#define OFF_PAR1   (OFF_P2Q + (size_t)512*256*4)                 // float2 [256]
#define OFF_PAR2   (OFF_PAR1 + (size_t)256*8)
#define OFF_WP1    (OFF_PAR2 + (size_t)256*8)                    // 16 slabs x 32KB
#define OFF_WP2    (OFF_WP1 + (size_t)524288)                    // 8 slabs x 32KB

__device__ __forceinline__ f4 relu4(f4 v) {
    v.x = fmaxf(v.x, 0.f); v.y = fmaxf(v.y, 0.f);
    v.z = fmaxf(v.z, 0.f); v.w = fmaxf(v.w, 0.f);
    return v;
}

__device__ __forceinline__ ushort bfrn(float x) {
    unsigned u = __float_as_uint(x);
    return (ushort)((u + 0x7FFFu + ((u >> 16) & 1u)) >> 16);
}
__device__ __forceinline__ void split1(float v, ushort& h, ushort& lo) {
    h = bfrn(v);
    float hf = __uint_as_float(((unsigned)h) << 16);
    lo = bfrn(v - hf);
}
__device__ __forceinline__ uint4 pack8(const ushort* h) {
    uint4 u;
    u.x = (unsigned)h[0] | ((unsigned)h[1] << 16);
    u.y = (unsigned)h[2] | ((unsigned)h[3] << 16);
    u.z = (unsigned)h[4] | ((unsigned)h[5] << 16);
    u.w = (unsigned)h[6] | ((unsigned)h[7] << 16);
    return u;
}

// ---- 1. weight split + pre-swizzle into per-k-step LDS image ----
__global__ void k_wsplit(const float* __restrict__ w1, const float* __restrict__ w2,
                         uint4* __restrict__ wp1, uint4* __restrict__ wp2) {
    int i = blockIdx.x * 256 + threadIdx.x;          // 16384 w1 chunks + 8192 w2
    const float* src; uint4* dst; int kt, o, kh, kdim;
    if (i < 16384) { kdim = 512; kt = i >> 10; int r = i & 1023; o = r >> 2; kh = r & 3; src = w1; dst = wp1; }
    else { int j = i - 16384; kdim = 256; kt = j >> 10; int r = j & 1023; o = r >> 2; kh = r & 3; src = w2; dst = wp2; }
    const float* p = src + o * kdim + kt * 32 + kh * 8;
    ushort hh[8], ll[8];
    #pragma unroll
    for (int k = 0; k < 8; ++k) split1(p[k], hh[k], ll[k]);
    uint4* slab = dst + kt * 2048 + o * 8;
    slab[kh ^ (o & 7)] = pack8(hh);
    slab[(kh + 4) ^ (o & 7)] = pack8(ll);
}

// ---- 2. three-NN: branchless insert (wave64 makes any screen branch ~always-taken) ----
__device__ __forceinline__ void ins3(float d, int i,
                                     float& d0, int& i0, float& d1, int& i1,
                                     float& d2, int& i2) {
    bool c2 = d < d2, c1 = d < d1, c0 = d < d0;
    d2 = c1 ? d1 : (c2 ? d : d2);  i2 = c1 ? i1 : (c2 ? i : i2);
    d1 = c0 ? d0 : (c1 ? d : d1);  i1 = c0 ? i0 : (c1 ? i : i1);
    d0 = c0 ? d  : d0;             i0 = c0 ? i  : i0;
}

__global__ __launch_bounds__(256) void k_threenn(const float* __restrict__ pc,
                                                 const float* __restrict__ cen,
                                                 int* __restrict__ idx,
                                                 float* __restrict__ wgt) {
    __shared__ f4 c4[MM + 4];
    const int b  = blockIdx.x >> 7;
    const int n0 = (blockIdx.x & 127) << 6;
    const float* cb = cen + b * 3 * MM;
    for (int m = threadIdx.x; m < MM; m += 256) {
        f4 v = {cb[m], cb[MM + m], cb[2 * MM + m], 0.f};
        c4[m + (m >> 9)] = v;
    }
    __syncthreads();
    const int pt  = threadIdx.x >> 2;
    const int sub = threadIdx.x & 3;
    const int n = n0 + pt;
    const float* pb = pc + b * 3 * NN;
    const float px = pb[n], py = pb[NN + n], pz = pb[2 * NN + n];
    float d0 = 3e38f, d1 = 3e38f, d2 = 3e38f;
    int   i0 = 0,    i1 = 0,    i2 = 0;
    const f4* cbase = c4 + sub * 513;
    const int m0 = sub * 512;
    for (int mm = 0; mm < 512; mm += 8) {
        #pragma unroll
        for (int u = 0; u < 8; ++u) {
            f4 cm = cbase[mm + u];
            float dx = px - cm.x, dy = py - cm.y, dz = pz - cm.z;
            float d = fmaf(dz, dz, fmaf(dy, dy, dx * dx));
            ins3(d, m0 + mm + u, d0, i0, d1, i1, d2, i2);
        }
    }
    #pragma unroll
    for (int m = 1; m <= 2; m <<= 1) {
        float e0 = __shfl_xor(d0, m), e1 = __shfl_xor(d1, m), e2 = __shfl_xor(d2, m);
        int   j0 = __shfl_xor(i0, m), j1 = __shfl_xor(i1, m), j2 = __shfl_xor(i2, m);
        ins3(e0, j0, d0, i0, d1, i1, d2, i2);
        ins3(e1, j1, d0, i0, d1, i1, d2, i2);
        ins3(e2, j2, d0, i0, d1, i1, d2, i2);
    }
    if (sub == 0) {
        float w0 = 1.f / (d0 + 1e-8f), w1 = 1.f / (d1 + 1e-8f), w2 = 1.f / (d2 + 1e-8f);
        float inv = 1.f / (w0 + w1 + w2);
        const int p = b * NN + n;
        *(int4*)(idx + p * 4) = make_int4(i0, i1, i2, 0);
        f4 wv = {w0 * inv, w1 * inv, w2 * inv, 0.f};
        *(f4*)(wgt + p * 4) = wv;
    }
}

// ---- 3. gather-interpolate, LDS-staged ----
__global__ __launch_bounds__(512) void k_interp(const float* __restrict__ cf,
                                                const int* __restrict__ idx,
                                                const float* __restrict__ wgt,
                                                float* __restrict__ itp) {
    __shared__ float2 l2[4][MM];                     // 8 rows pair-packed: 64 KB
    const int blk = blockIdx.x;
    const int b  = blk >> 6;                         // 64 blocks/batch: 32 cg x 2 nh
    const int cg = (blk >> 1) & 31;
    const int nh = blk & 1;
    const int tid = threadIdx.x;
    const float* cbase = cf + ((size_t)b * CF + cg * 8) * MM;
    #pragma unroll
    for (int q = 0; q < 4; ++q) {
        f4 ae = *(const f4*)(cbase + (2 * q) * MM + tid * 4);
        f4 ao = *(const f4*)(cbase + (2 * q + 1) * MM + tid * 4);
        #pragma unroll
        for (int i = 0; i < 4; ++i) l2[q][tid * 4 + i] = make_float2(ae[i], ao[i]);
    }
    __syncthreads();
    const int nb = nh * 4096;
    float* op = itp + ((size_t)b * CF + cg * 8) * NN + nb;
    #pragma unroll 2
    for (int it = 0; it < 8; ++it) {
        const int nn = it * 512 + tid;
        const int p = b * NN + nb + nn;
        const int4 iv = *(const int4*)(idx + p * 4);
        const f4   wv = *(const f4*)(wgt + p * 4);
        #pragma unroll
        for (int q = 0; q < 4; ++q) {
            float2 v0 = l2[q][iv.x], v1 = l2[q][iv.y], v2 = l2[q][iv.z];
            float sx = fmaf(v0.x, wv.x, fmaf(v1.x, wv.y, v2.x * wv.z));
            float sy = fmaf(v0.y, wv.x, fmaf(v1.y, wv.y, v2.y * wv.z));
            op[(size_t)(2 * q) * NN + nn]     = sx;
            op[(size_t)(2 * q + 1) * NN + nn] = sy;
        }
    }
}

// ---- 4/6. split-bf16 MFMA GEMM ----
template<int KDIM, bool BNIN>
__global__ __launch_bounds__(256, 2) void k_gemm(const float* xa,
                                                 const float* __restrict__ xb,
                                                 const uint4* __restrict__ wp,
                                                 float* yo,
                                                 const float2* __restrict__ par,
                                                 float* __restrict__ ps,
                                                 float* __restrict__ pq) {
    __shared__ __align__(16) unsigned char lds[49152];   // X 16KB | W 32KB
    const int tid = threadIdx.x;
    const int b  = blockIdx.x >> 6;
    const int n0 = (blockIdx.x & 63) << 7;
    const int nl = tid & 127;
    const int kq = (tid >> 7) << 4;
    const int l = tid & 63, w = tid >> 6;
    const int lr = l & 15, lk = l >> 4;
    const int sw = (nl & 7) << 4;
    const int h0 = kq >> 3;

    f4 acc[4][8];
    #pragma unroll
    for (int mo = 0; mo < 4; ++mo)
        #pragma unroll
        for (int nn = 0; nn < 8; ++nn) acc[mo][nn] = (f4){0.f, 0.f, 0.f, 0.f};

    float xp[16];
    {
        const float* s = xa + ((size_t)b * 256 + kq) * NN + n0 + nl;
        #pragma unroll
        for (int i = 0; i < 16; ++i) xp[i] = s[i * NN];
    }

    for (int kt = 0; kt < KDIM / 32; ++kt) {
        const int c0 = kt * 32 + kq;
        __syncthreads();
        {
            ushort hh[16], ll[16];
            #pragma unroll
            for (int i = 0; i < 16; ++i) {
                float v = xp[i];
                if constexpr (BNIN) {
                    float2 pr = par[c0 + i];
                    v = fmaxf(fmaf(v, pr.x, pr.y), 0.f);
                }
                split1(v, hh[i], ll[i]);
            }
            const int xrow = nl << 7;
            *(uint4*)(lds + xrow + (((h0    ) << 4) ^ sw)) = pack8(hh);
            *(uint4*)(lds + xrow + (((h0 + 1) << 4) ^ sw)) = pack8(hh + 8);
            *(uint4*)(lds + xrow + (((h0 + 4) << 4) ^ sw)) = pack8(ll);
            *(uint4*)(lds + xrow + (((h0 + 5) << 4) ^ sw)) = pack8(ll + 8);
        }
        {
            const uint4* wsrc = wp + kt * 2048 + tid;
            #pragma unroll
            for (int c = 0; c < 8; ++c) {
                uint4 v = wsrc[c * 256];
                *(uint4*)(lds + 16384 + c * 4096 + tid * 16) = v;
            }
        }
        __syncthreads();
        if (kt + 1 < KDIM / 32) {
            const int c1 = (kt + 1) * 32 + kq;
            const float* s = (KDIM == 512 && c1 >= 256)
                ? xb + ((size_t)b * 256 + (c1 - 256)) * NN + n0 + nl
                : xa + ((size_t)b * 256 + c1) * NN + n0 + nl;
            #pragma unroll
            for (int i = 0; i < 16; ++i) xp[i] = s[i * NN];
        }
        U4 Ah[4], Al[4];
        #pragma unroll
        for (int mo = 0; mo < 4; ++mo) {
            const int o = w * 64 + mo * 16 + lr;
            const unsigned char* r = lds + 16384 + o * 128;
            const int osw = (o & 7) << 4;
            Ah[mo].u = *(const uint4*)(r + ((lk << 4) ^ osw));
            Al[mo].u = *(const uint4*)(r + ((64 + (lk << 4)) ^ osw));
        }
        #pragma unroll
        for (int nn = 0; nn < 8; ++nn) {
            const int n = nn * 16 + lr;
            const unsigned char* r = lds + n * 128;
            const int nsw = (n & 7) << 4;
            U4 Bh, Bl;
            Bh.u = *(const uint4*)(r + ((lk << 4) ^ nsw));
            Bl.u = *(const uint4*)(r + ((64 + (lk << 4)) ^ nsw));
            #pragma unroll
            for (int mo = 0; mo < 4; ++mo)
                acc[mo][nn] = __builtin_amdgcn_mfma_f32_16x16x32_bf16(Ah[mo].s, Bh.s, acc[mo][nn], 0, 0, 0);
            #pragma unroll
            for (int mo = 0; mo < 4; ++mo)
                acc[mo][nn] = __builtin_amdgcn_mfma_f32_16x16x32_bf16(Al[mo].s, Bh.s, acc[mo][nn], 0, 0, 0);
            #pragma unroll
            for (int mo = 0; mo < 4; ++mo)
                acc[mo][nn] = __builtin_amdgcn_mfma_f32_16x16x32_bf16(Ah[mo].s, Bl.s, acc[mo][nn], 0, 0, 0);
        }
    }

    float sv[4][4], qv[4][4];
    #pragma unroll
    for (int mo = 0; mo < 4; ++mo)
        #pragma unroll
        for (int j = 0; j < 4; ++j) { sv[mo][j] = 0.f; qv[mo][j] = 0.f; }
    #pragma unroll
    for (int mo = 0; mo < 4; ++mo)
        #pragma unroll
        for (int nn = 0; nn < 8; ++nn)
            #pragma unroll
            for (int j = 0; j < 4; ++j) {
                float a = acc[mo][nn][j];
                sv[mo][j] += a; qv[mo][j] += a * a;
            }
    #pragma unroll
    for (int m = 1; m < 16; m <<= 1)
        #pragma unroll
        for (int mo = 0; mo < 4; ++mo)
            #pragma unroll
            for (int j = 0; j < 4; ++j) {
                sv[mo][j] += __shfl_xor(sv[mo][j], m, 64);
                qv[mo][j] += __shfl_xor(qv[mo][j], m, 64);
            }
    if (lr == 0) {
        #pragma unroll
        for (int mo = 0; mo < 4; ++mo) {
            const int o0 = w * 64 + mo * 16 + lk * 4;
            f4 vs = {sv[mo][0], sv[mo][1], sv[mo][2], sv[mo][3]};
            f4 vq = {qv[mo][0], qv[mo][1], qv[mo][2], qv[mo][3]};
            *(f4*)(ps + blockIdx.x * 256 + o0) = vs;
            *(f4*)(pq + blockIdx.x * 256 + o0) = vq;
        }
    }
    float* yb = yo + (size_t)b * 256 * NN + n0;
    #pragma unroll
    for (int mo = 0; mo < 4; ++mo)
        #pragma unroll
        for (int j = 0; j < 4; ++j) {
            float* row = yb + (size_t)(w * 64 + mo * 16 + lk * 4 + j) * NN + lr;
            #pragma unroll
            for (int nn = 0; nn < 8; ++nn) row[nn * 16] = acc[mo][nn][j];
        }
}

// ---- 5/7. BN stats -> (scale, shift) ----
__global__ void k_params(const float* __restrict__ ps, const float* __restrict__ pq,
                         const float* __restrict__ gamma, const float* __restrict__ beta,
                         float2* __restrict__ out) {
    __shared__ float rs[256], rq[256];
    const int oo = threadIdx.x & 15, seg = threadIdx.x >> 4;
    const int o = blockIdx.x * 16 + oo;
    float s = 0.f, q = 0.f;
    for (int blk = seg; blk < 512; blk += 16) {
        s += ps[blk * 256 + o];
        q += pq[blk * 256 + o];
    }
    rs[threadIdx.x] = s; rq[threadIdx.x] = q;
    __syncthreads();
    if (seg == 0) {
        float S = 0.f, Q = 0.f;
        #pragma unroll
        for (int g = 0; g < 16; ++g) { S += rs[g * 16 + oo]; Q += rq[g * 16 + oo]; }
        float mean = S * (1.f / 65536.f);
        float var  = Q * (1.f / 65536.f) - mean * mean;
        float rstd = rsqrtf(var + 1e-5f);
        float sc = gamma[o] * rstd;
        out[o] = make_float2(sc, beta[o] - mean * sc);
    }
}

// ---- 8. final in-place BN+relu ----
__global__ __launch_bounds__(256) void k_final(float* __restrict__ yy,
                                               const float2* __restrict__ par) {
    int i = blockIdx.x * 256 + threadIdx.x;
    #pragma unroll 4
    for (int t = i; t < 4194304; t += 524288) {
        f4 v = ((f4*)yy)[t];
        float2 pr = par[(t >> 11) & 255];
        v = relu4(v * pr.x + pr.y);
        ((f4*)yy)[t] = v;
    }
}

extern "C" void kernel_launch(void* const* d_in, const int* in_sizes, int n_in,
                              void* d_out, int out_size, void* d_ws, size_t ws_size,
                              hipStream_t stream) {
    const float* pc  = (const float*)d_in[0];
    const float* cen = (const float*)d_in[1];
    const float* cf  = (const float*)d_in[2];
    const float* pf  = (const float*)d_in[3];
    const float* w1  = (const float*)d_in[4];
    const float* g1  = (const float*)d_in[6];
    const float* be1 = (const float*)d_in[7];
    const float* w2  = (const float*)d_in[8];
    const float* g2  = (const float*)d_in[10];
    const float* be2 = (const float*)d_in[11];

    char* ws = (char*)d_ws;
    int*    idx  = (int*)  (ws + OFF_IDX);
    float*  wgt  = (float*)(ws + OFF_WGT);
    float*  itp  = (float*)(ws + OFF_INTERP);
    float*  p1s  = (float*)(ws + OFF_P1S);
    float*  p1q  = (float*)(ws + OFF_P1Q);
    float*  p2s  = (float*)(ws + OFF_P2S);
    float*  p2q  = (float*)(ws + OFF_P2Q);
    float2* par1 = (float2*)(ws + OFF_PAR1);
    float2* par2 = (float2*)(ws + OFF_PAR2);
    uint4*  wp1  = (uint4*)(ws + OFF_WP1);
    uint4*  wp2  = (uint4*)(ws + OFF_WP2);
    float*  out  = (float*)d_out;

    k_wsplit<<<96, 256, 0, stream>>>(w1, w2, wp1, wp2);
    k_threenn<<<1024, 256, 0, stream>>>(pc, cen, idx, wgt);
    k_interp<<<512, 512, 0, stream>>>(cf, idx, wgt, itp);
    k_gemm<512, false><<<512, 256, 0, stream>>>(itp, pf, wp1, out, par1, p1s, p1q);
    k_params<<<16, 256, 0, stream>>>(p1s, p1q, g1, be1, par1);
    k_gemm<256, true><<<512, 256, 0, stream>>>(out, out, wp2, out, par1, p2s, p2q);
    k_params<<<16, 256, 0, stream>>>(p2s, p2q, g2, be2, par2);
    k_final<<<2048, 256, 0, stream>>>(out, par2);
    (void)hipMemcpyAsync(out + 16777216, pc, (size_t)BB * 3 * NN * 4,
                         hipMemcpyDeviceToDevice, stream);
}